// Round 8
// baseline (42.008 us; speedup 1.0000x reference)
//
#include <hip/hip_runtime.h>
#include <hip/hip_bf16.h>
#include <math.h>

// S4 SSKernelNPLR, split into two kernels (phase-split measurable in rocprof):
//   cauchy_kernel: Cauchy sum + Woodbury at 2049 rfft nodes -> K spectrum in
//     d_ws. 4 bins/thread (2 packed v2f chains), pole data as 5x float4 LDS
//     broadcasts (ds_read_b128), z = 2i*tan(pi*l/L) via HW sin/cos.
//   ifft_kernel: Hermitian recombination (fused into round-1 register loads,
//     branch-free) + 2048-pt inverse FFT as radix-8,8,8,4 (8 pts/thread in
//     registers, 4 barriers), digit-reversed output via padded LDS.
// Pad ZP(i)=i+(i>>4)+(i>>8) keeps stride-2^k stage reads AND the bit-reversed
// output reads at <=4-way conflicts (old pad left a 32-way on output).
// Fallback (ws too small): round-7 fused kernel.
// Dims hardcoded: H=512, N=64, R=1, CH=1, L=4096.

#define HH   512
#define NN   64
#define LLEN 4096
#define MM   2048
#define WS_STRIDE 2056          // float2 per head in ws (2049 used, padded)
#define ZP(i) ((i) + ((i) >> 4) + ((i) >> 8))
#define ZPAD(i) ((i) + ((i) >> 4))   // fused-fallback pad

typedef float v2f __attribute__((ext_vector_type(2)));

__device__ __forceinline__ float sinr(float r) { return __builtin_amdgcn_sinf(r); }  // sin(2*pi*r)
__device__ __forceinline__ float cosr(float r) { return __builtin_amdgcn_cosf(r); }
__device__ __forceinline__ float rcpf(float x) { return __builtin_amdgcn_rcpf(x); }

// ---------------- Cauchy kernel (phases 1-2) ----------------
// grid = 2 blocks per head (chunk = low bit), 256 threads.
// thread owns bins {l0, l0+1024} (pair A) and {l0+512, l0+1536} (pair B),
// l0 = chunk*256 + tid in [0,512).

__device__ __forceinline__ void cauchy_step(
    const v2f tv, const v2f mwi, const v2f nr, const v2f wr2,
    const v2f v00r, const v2f v00i, const v2f v01r, const v2f v01i,
    const v2f v10r, const v2f v10i, const v2f v11,
    v2f& a00r, v2f& a00i, v2f& a01r, v2f& a01i,
    v2f& a10r, v2f& a10i, v2f& a11r, v2f& a11i)
{
    const v2f dim = __builtin_elementwise_fma(tv, (v2f){2.0f, 2.0f}, mwi); // 2t - wi
    const v2f den = __builtin_elementwise_fma(dim, dim, wr2);
    const float ip = rcpf(den.x * den.y);      // one rcp for both halves
    v2f inv; inv.x = den.y * ip; inv.y = den.x * ip;
    const v2f ur = nr * inv;
    const v2f ui = -(dim * inv);
    a00r = __builtin_elementwise_fma( v00r, ur, a00r);
    a00r = __builtin_elementwise_fma(-v00i, ui, a00r);
    a00i = __builtin_elementwise_fma( v00r, ui, a00i);
    a00i = __builtin_elementwise_fma( v00i, ur, a00i);
    a01r = __builtin_elementwise_fma( v01r, ur, a01r);
    a01r = __builtin_elementwise_fma(-v01i, ui, a01r);
    a01i = __builtin_elementwise_fma( v01r, ui, a01i);
    a01i = __builtin_elementwise_fma( v01i, ur, a01i);
    a10r = __builtin_elementwise_fma( v10r, ur, a10r);
    a10r = __builtin_elementwise_fma(-v10i, ui, a10r);
    a10i = __builtin_elementwise_fma( v10r, ui, a10i);
    a10i = __builtin_elementwise_fma( v10i, ur, a10i);
    a11r = __builtin_elementwise_fma( v11,  ur, a11r);
    a11i = __builtin_elementwise_fma( v11,  ui, a11i);
}

__device__ __forceinline__ void woodbury_K(
    const v2f tv,
    const v2f a00r, const v2f a00i, const v2f a01r, const v2f a01i,
    const v2f a10r, const v2f a10i, const v2f a11r, const v2f a11i,
    v2f& Kr, v2f& Ki)
{
    const v2f dr = a11r + 1.0f;
    const v2f di = a11i;
    const v2f dd = __builtin_elementwise_fma(dr, dr, di * di);
    v2f dinv; dinv.x = rcpf(dd.x); dinv.y = rcpf(dd.y);
    const v2f numr = a01r * a10r - a01i * a10i;
    const v2f numi = a01r * a10i + a01i * a10r;
    const v2f cr = (numr * dr + numi * di) * dinv;
    const v2f ci = (numi * dr - numr * di) * dinv;
    const v2f Wr = a00r - cr;
    const v2f Wi = a00i - ci;
    Kr = __builtin_elementwise_fma(-tv, Wi, Wr);   // K = W * (1 + i*t)
    Ki = __builtin_elementwise_fma( tv, Wr, Wi);
}

__global__ __launch_bounds__(256, 6) void cauchy_kernel(
    const float* __restrict__ log_dt,
    const float* __restrict__ w_re, const float* __restrict__ w_im,
    const float* __restrict__ B_re, const float* __restrict__ B_im,
    const float* __restrict__ P_re, const float* __restrict__ P_im,
    const float* __restrict__ C_re, const float* __restrict__ C_im,
    float2* __restrict__ Kout)
{
    __shared__ float4 s_p4[NN][5];   // 5 KB; scalars duplicated as (v,v) halves

    const int blk   = blockIdx.x;
    const int h     = blk >> 1;
    const int chunk = blk & 1;
    const int tid   = threadIdx.x;

    if (tid < NN) {
        const int n   = tid;
        const int idx = h * NN + n;
        const float dt = expf(log_dt[h]);
        const float wr = w_re[idx] * dt;
        const float wi = w_im[idx] * dt;
        const float Br = B_re[idx], Bi = B_im[idx];
        const float Pr = P_re[idx], Pi = P_im[idx];
        const float Cr = C_re[idx], Ci = C_im[idx];
        const float v00r = dt * (Br * Cr - Bi * Ci);
        const float v00i = dt * (Br * Ci + Bi * Cr);
        const float v01r = dt * (Br * Pr + Bi * Pi);   // B*conj(P)
        const float v01i = dt * (Bi * Pr - Br * Pi);
        const float v10r = dt * (Pr * Cr - Pi * Ci);
        const float v10i = dt * (Pr * Ci + Pi * Cr);
        const float v11  = dt * (Pr * Pr + Pi * Pi);
        s_p4[n][0] = make_float4(-wi, -wi, -wr, -wr);
        s_p4[n][1] = make_float4(wr * wr, wr * wr, v00r, v00r);
        s_p4[n][2] = make_float4(v00i, v00i, v01r, v01r);
        s_p4[n][3] = make_float4(v01i, v01i, v10r, v10r);
        s_p4[n][4] = make_float4(v10i, v10i, v11, v11);
    }
    __syncthreads();

    const int l0 = chunk * 256 + tid;   // [0,512)
    v2f tvA, tvB;
    {
        const float rA0 = (float)l0            * (1.0f / 8192.0f);
        const float rA1 = (float)(l0 + 1024)   * (1.0f / 8192.0f);
        const float rB0 = (float)(l0 + 512)    * (1.0f / 8192.0f);
        const float rB1 = (float)(l0 + 1536)   * (1.0f / 8192.0f);
        tvA.x = sinr(rA0) * rcpf(cosr(rA0));
        tvA.y = sinr(rA1) * rcpf(cosr(rA1));
        tvB.x = sinr(rB0) * rcpf(cosr(rB0));
        tvB.y = sinr(rB1) * rcpf(cosr(rB1));
    }

    v2f A00r = 0.f, A00i = 0.f, A01r = 0.f, A01i = 0.f;
    v2f A10r = 0.f, A10i = 0.f, A11r = 0.f, A11i = 0.f;
    v2f B00r = 0.f, B00i = 0.f, B01r = 0.f, B01i = 0.f;
    v2f B10r = 0.f, B10i = 0.f, B11r = 0.f, B11i = 0.f;

    for (int n = 0; n < NN; ++n) {
        const float4 f0 = s_p4[n][0];
        const float4 f1 = s_p4[n][1];
        const float4 f2 = s_p4[n][2];
        const float4 f3 = s_p4[n][3];
        const float4 f4 = s_p4[n][4];
        const v2f mwi  = {f0.x, f0.y}, nr   = {f0.z, f0.w};
        const v2f wr2  = {f1.x, f1.y}, v00r = {f1.z, f1.w};
        const v2f v00i = {f2.x, f2.y}, v01r = {f2.z, f2.w};
        const v2f v01i = {f3.x, f3.y}, v10r = {f3.z, f3.w};
        const v2f v10i = {f4.x, f4.y}, v11  = {f4.z, f4.w};
        cauchy_step(tvA, mwi, nr, wr2, v00r, v00i, v01r, v01i, v10r, v10i, v11,
                    A00r, A00i, A01r, A01i, A10r, A10i, A11r, A11i);
        cauchy_step(tvB, mwi, nr, wr2, v00r, v00i, v01r, v01i, v10r, v10i, v11,
                    B00r, B00i, B01r, B01i, B10r, B10i, B11r, B11i);
    }

    float2* __restrict__ Kh = Kout + (size_t)h * WS_STRIDE;
    {
        v2f Kr, Ki;
        woodbury_K(tvA, A00r, A00i, A01r, A01i, A10r, A10i, A11r, A11i, Kr, Ki);
        Kh[l0]        = make_float2(Kr.x, (l0 == 0) ? 0.0f : Ki.x);  // bin 0 imag unused
        Kh[l0 + 1024] = make_float2(Kr.y, Ki.y);
    }
    {
        v2f Kr, Ki;
        woodbury_K(tvB, B00r, B00i, B01r, B01i, B10r, B10i, B11r, B11i, Kr, Ki);
        Kh[l0 + 512]  = make_float2(Kr.x, Ki.x);
        Kh[l0 + 1536] = make_float2(Kr.y, Ki.y);
    }
    // Nyquist bin K[2048]: analytic z->inf limit, real only
    if (chunk == 0 && tid == 0) {
        float sr = 0.f;
        for (int n = 0; n < NN; ++n) sr += s_p4[n][1].z;   // v00r
        Kh[MM] = make_float2(0.5f * sr, 0.0f);
    }
}

// ---------------- iFFT kernel (recombination + 2048-pt inverse FFT) ----------------
// Inverse DFT with omega = e^{+2pi i/N}, DIF radix-8,8,8,4; natural in,
// bitrev(11) out (identical permutation to the verified radix-2 cascade).

__device__ __forceinline__ void radix8(float xr[8], float xi[8], const float rev)
{
    const float c   = cosr(rev), s = sinr(rev);           // W1 = e^{2pi i rev}
    const float w2r = c * c - s * s, w2i = 2.0f * c * s;  // W2 = W1^2
    const float w4r = w2r * w2r - w2i * w2i;              // W4 = W2^2
    const float w4i = 2.0f * w2r * w2i;
    const float RH  = 0.70710678118654752440f;
    const float cms = RH * (c - s), cps = RH * (c + s);   // W1*w8 = (cms,cps)

    // stage A (span 4): B_q = (x_q - x_{q+4}) * W1*w8^q
    const float Ar0 = xr[0] + xr[4], Ai0 = xi[0] + xi[4];
    const float Ar1 = xr[1] + xr[5], Ai1 = xi[1] + xi[5];
    const float Ar2 = xr[2] + xr[6], Ai2 = xi[2] + xi[6];
    const float Ar3 = xr[3] + xr[7], Ai3 = xi[3] + xi[7];
    float dr, di;
    dr = xr[0] - xr[4]; di = xi[0] - xi[4];
    const float Br0 = dr * c - di * s,      Bi0 = dr * s + di * c;
    dr = xr[1] - xr[5]; di = xi[1] - xi[5];
    const float Br1 = dr * cms - di * cps,  Bi1 = dr * cps + di * cms;
    dr = xr[2] - xr[6]; di = xi[2] - xi[6];                     // * i*W1 = (-s,c)
    const float Br2 = -dr * s - di * c,     Bi2 = dr * c - di * s;
    dr = xr[3] - xr[7]; di = xi[3] - xi[7];                     // * W1*w8^3 = (-cps,cms)
    const float Br3 = -dr * cps - di * cms, Bi3 = dr * cms - di * cps;

    // stage B (span 2): twiddles W2, i*W2
    const float Cr0 = Ar0 + Ar2, Ci0 = Ai0 + Ai2;
    const float Cr1 = Ar1 + Ar3, Ci1 = Ai1 + Ai3;
    dr = Ar0 - Ar2; di = Ai0 - Ai2;
    const float Dr0 = dr * w2r - di * w2i,  Di0 = dr * w2i + di * w2r;
    dr = Ar1 - Ar3; di = Ai1 - Ai3;                             // * i*W2 = (-w2i,w2r)
    const float Dr1 = -dr * w2i - di * w2r, Di1 = dr * w2r - di * w2i;
    const float Er0 = Br0 + Br2, Ei0 = Bi0 + Bi2;
    const float Er1 = Br1 + Br3, Ei1 = Bi1 + Bi3;
    dr = Br0 - Br2; di = Bi0 - Bi2;
    const float Fr0 = dr * w2r - di * w2i,  Fi0 = dr * w2i + di * w2r;
    dr = Br1 - Br3; di = Bi1 - Bi3;
    const float Fr1 = -dr * w2i - di * w2r, Fi1 = dr * w2r - di * w2i;

    // stage C (span 1): twiddle W4 on odd slots
    xr[0] = Cr0 + Cr1; xi[0] = Ci0 + Ci1;
    dr = Cr0 - Cr1; di = Ci0 - Ci1;
    xr[1] = dr * w4r - di * w4i; xi[1] = dr * w4i + di * w4r;
    xr[2] = Dr0 + Dr1; xi[2] = Di0 + Di1;
    dr = Dr0 - Dr1; di = Di0 - Di1;
    xr[3] = dr * w4r - di * w4i; xi[3] = dr * w4i + di * w4r;
    xr[4] = Er0 + Er1; xi[4] = Ei0 + Ei1;
    dr = Er0 - Er1; di = Ei0 - Ei1;
    xr[5] = dr * w4r - di * w4i; xi[5] = dr * w4i + di * w4r;
    xr[6] = Fr0 + Fr1; xi[6] = Fi0 + Fi1;
    dr = Fr0 - Fr1; di = Fi0 - Fi1;
    xr[7] = dr * w4r - di * w4i; xi[7] = dr * w4i + di * w4r;
}

__global__ __launch_bounds__(256, 2) void ifft_kernel(
    const float2* __restrict__ Kg, float* __restrict__ out)
{
    __shared__ float2 s_Z[ZP(MM - 1) + 1];   // 2182 float2 = 17.5 KB

    const int h = blockIdx.x;
    const int t = threadIdx.x;
    const float2* __restrict__ Kh = Kg + (size_t)h * WS_STRIDE;

    float xr[8], xi[8];

    // ---- round 1: Hermitian recombination (global->reg, branch-free) + radix-8 ----
    // Z[k] = (Pr - (s*Dr + c*Di), Pi + (c*Dr - s*Di)), (c,s)=e^{2pi i k/4096};
    // valid for ALL k in [0,2047] given K[0].y = K[2048].y = 0.
    #pragma unroll
    for (int q = 0; q < 8; ++q) {
        const int m = t + (q << 8);
        const float2 Ka = Kh[m];
        const float2 Kb = Kh[MM - m];
        const float rev = (float)m * (1.0f / 4096.0f);
        const float sk = sinr(rev), ck = cosr(rev);
        const float Pr = 0.5f * (Ka.x + Kb.x), Pi = 0.5f * (Ka.y - Kb.y);
        const float Dr = 0.5f * (Ka.x - Kb.x), Di = 0.5f * (Ka.y + Kb.y);
        xr[q] = Pr - (sk * Dr + ck * Di);
        xi[q] = Pi + (ck * Dr - sk * Di);
    }
    radix8(xr, xi, (float)t * (1.0f / 2048.0f));        // stages 10,9,8
    #pragma unroll
    for (int q = 0; q < 8; ++q) {
        const int i = t + (q << 8);
        s_Z[ZP(i)] = make_float2(xr[q], xi[q]);
    }
    __syncthreads();

    // ---- round 2: stages 7,6,5 (blocks of 256, stride 32) ----
    {
        const int base = ((t >> 5) << 8) + (t & 31);
        #pragma unroll
        for (int q = 0; q < 8; ++q) {
            const float2 z = s_Z[ZP(base + (q << 5))];
            xr[q] = z.x; xi[q] = z.y;
        }
        radix8(xr, xi, (float)(t & 31) * (1.0f / 256.0f));
        #pragma unroll
        for (int q = 0; q < 8; ++q)
            s_Z[ZP(base + (q << 5))] = make_float2(xr[q], xi[q]);
    }
    __syncthreads();

    // ---- round 3: stages 4,3,2 (blocks of 32, stride 4) ----
    {
        const int base = ((t >> 2) << 5) + (t & 3);
        #pragma unroll
        for (int q = 0; q < 8; ++q) {
            const float2 z = s_Z[ZP(base + (q << 2))];
            xr[q] = z.x; xi[q] = z.y;
        }
        radix8(xr, xi, (float)(t & 3) * (1.0f / 32.0f));
        #pragma unroll
        for (int q = 0; q < 8; ++q)
            s_Z[ZP(base + (q << 2))] = make_float2(xr[q], xi[q]);
    }
    __syncthreads();

    // ---- round 4: stages 1,0 = two radix-4 groups on 8 contiguous points ----
    {
        const int i0 = t << 3;
        #pragma unroll
        for (int q = 0; q < 8; ++q) {
            const float2 z = s_Z[ZP(i0 + q)];
            xr[q] = z.x; xi[q] = z.y;
        }
        #pragma unroll
        for (int g = 0; g < 2; ++g) {
            const int o = g * 4;
            const float A0r = xr[o] + xr[o+2], A0i = xi[o] + xi[o+2];
            const float A1r = xr[o+1] + xr[o+3], A1i = xi[o+1] + xi[o+3];
            const float B0r = xr[o] - xr[o+2], B0i = xi[o] - xi[o+2];
            const float B1r = -(xi[o+1] - xi[o+3]);      // (p1-p3)*i
            const float B1i =  (xr[o+1] - xr[o+3]);
            xr[o]   = A0r + A1r; xi[o]   = A0i + A1i;
            xr[o+1] = A0r - A1r; xi[o+1] = A0i - A1i;
            xr[o+2] = B0r + B1r; xi[o+2] = B0i + B1i;
            xr[o+3] = B0r - B1r; xi[o+3] = B0i - B1i;
        }
        #pragma unroll
        for (int q = 0; q < 8; ++q)
            s_Z[ZP(i0 + q)] = make_float2(xr[q], xi[q]);
    }
    __syncthreads();

    // ---- output: z[m] = X[bitrev11(m)]; x[2m]=Re/M, x[2m+1]=Im/M ----
    const float scale = 1.0f / (float)MM;
    float2* o2 = (float2*)out + (size_t)h * MM;
    #pragma unroll
    for (int q = 0; q < 8; ++q) {
        const int m = t + (q << 8);
        const int r = (int)(__brev((unsigned)m) >> 21);
        const float2 z = s_Z[ZP(r)];
        o2[m] = make_float2(z.x * scale, z.y * scale);
    }
}

// ---------------- fallback: round-7 fused kernel (ws too small) ----------------
__global__ __launch_bounds__(1024, 8) void ssknplr_fused(
    const float* __restrict__ log_dt,
    const float* __restrict__ w_re, const float* __restrict__ w_im,
    const float* __restrict__ B_re, const float* __restrict__ B_im,
    const float* __restrict__ P_re, const float* __restrict__ P_im,
    const float* __restrict__ C_re, const float* __restrict__ C_im,
    float* __restrict__ out)
{
    __shared__ v2f    s_pp[NN][10];
    __shared__ float2 s_Z[ZPAD(MM) + 1];

    const int h   = blockIdx.x;
    const int tid = threadIdx.x;

    if (tid < NN) {
        const int n   = tid;
        const int idx = h * NN + n;
        const float dt = expf(log_dt[h]);
        const float wr = w_re[idx] * dt;
        const float wi = w_im[idx] * dt;
        const float Br = B_re[idx], Bi = B_im[idx];
        const float Pr = P_re[idx], Pi = P_im[idx];
        const float Cr = C_re[idx], Ci = C_im[idx];
        const float vals[10] = {
            -wi, -wr, wr * wr,
            dt * (Br * Cr - Bi * Ci), dt * (Br * Ci + Bi * Cr),
            dt * (Br * Pr + Bi * Pi), dt * (Bi * Pr - Br * Pi),
            dt * (Pr * Cr - Pi * Ci), dt * (Pr * Ci + Pi * Cr),
            dt * (Pr * Pr + Pi * Pi)
        };
        #pragma unroll
        for (int j = 0; j < 10; ++j) s_pp[n][j] = (v2f){vals[j], vals[j]};
    }
    __syncthreads();

    v2f tv;
    {
        const float rx = (float)tid * (1.0f / 8192.0f);
        const float ry = (float)(tid + 1024) * (1.0f / 8192.0f);
        tv.x = sinr(rx) * rcpf(cosr(rx));
        tv.y = sinr(ry) * rcpf(cosr(ry));
    }
    v2f a00r = 0.f, a00i = 0.f, a01r = 0.f, a01i = 0.f;
    v2f a10r = 0.f, a10i = 0.f, a11r = 0.f, a11i = 0.f;
    for (int n = 0; n < NN; ++n) {
        cauchy_step(tv, s_pp[n][0], s_pp[n][1], s_pp[n][2], s_pp[n][3], s_pp[n][4],
                    s_pp[n][5], s_pp[n][6], s_pp[n][7], s_pp[n][8], s_pp[n][9],
                    a00r, a00i, a01r, a01i, a10r, a10i, a11r, a11i);
    }
    {
        v2f Kr, Ki;
        woodbury_K(tv, a00r, a00i, a01r, a01i, a10r, a10i, a11r, a11i, Kr, Ki);
        s_Z[ZPAD(tid)] = make_float2(Kr.x, (tid == 0) ? 0.0f : Ki.x);
        s_Z[ZPAD(tid + 1024)] = make_float2(Kr.y, Ki.y);
    }
    if (tid == 0) {
        float sr = 0.f;
        for (int n = 0; n < NN; ++n) sr += s_pp[n][3].x;
        s_Z[ZPAD(MM)] = make_float2(0.5f * sr, 0.0f);
    }
    __syncthreads();

    {
        const int k = tid;
        if (k == 0) {
            const float a = s_Z[ZPAD(0)].x;
            const float b = s_Z[ZPAD(MM)].x;
            s_Z[ZPAD(0)] = make_float2(0.5f * (a + b), 0.5f * (a - b));
            const float2 km = s_Z[ZPAD(MM / 2)];
            s_Z[ZPAD(MM / 2)] = make_float2(km.x, -km.y);
        } else {
            const float2 Ka = s_Z[ZPAD(k)];
            const float2 Kb = s_Z[ZPAD(MM - k)];
            const float rk = (float)k * (1.0f / 4096.0f);
            const float sk = sinr(rk), ck = cosr(rk);
            const float Pr = 0.5f * (Ka.x + Kb.x), Pi = 0.5f * (Ka.y - Kb.y);
            const float Dr = 0.5f * (Ka.x - Kb.x), Di = 0.5f * (Ka.y + Kb.y);
            const float al = sk * Dr + ck * Di;
            const float be = ck * Dr - sk * Di;
            s_Z[ZPAD(k)]      = make_float2(Pr - al, Pi + be);
            s_Z[ZPAD(MM - k)] = make_float2(Pr + al, be - Pi);
        }
    }
    __syncthreads();

    for (int s = 10; s >= 1; s -= 2) {
        const int Hh = 1 << s;
        const int Q = Hh >> 1;
        const float sc = rcpf((float)(2 * Hh));
        if (tid < 512) {
            const int b    = tid;
            const int j    = b & (Q - 1);
            const int base = ((b >> (s - 1)) << (s + 1)) + j;
            const int i0 = base, i1 = base + Q, i2 = base + Hh, i3 = base + Hh + Q;
            const float rev = (float)j * sc;
            const float c  = cosr(rev);
            const float sn = sinr(rev);
            const float wbr = c * c - sn * sn;
            const float wbi = 2.0f * c * sn;
            const float2 u0 = s_Z[ZPAD(i0)];
            const float2 u1 = s_Z[ZPAD(i1)];
            const float2 u2 = s_Z[ZPAD(i2)];
            const float2 u3 = s_Z[ZPAD(i3)];
            const float a0r = u0.x + u2.x, a0i = u0.y + u2.y;
            const float d0r = u0.x - u2.x, d0i = u0.y - u2.y;
            const float a1r = u1.x + u3.x, a1i = u1.y + u3.y;
            const float d1r = u1.x - u3.x, d1i = u1.y - u3.y;
            const float e0r = d0r * c - d0i * sn, e0i = d0r * sn + d0i * c;
            const float e1r = -(d1r * sn) - d1i * c, e1i = d1r * c - d1i * sn;
            s_Z[ZPAD(i0)] = make_float2(a0r + a1r, a0i + a1i);
            const float t0r = a0r - a1r, t0i = a0i - a1i;
            s_Z[ZPAD(i1)] = make_float2(t0r * wbr - t0i * wbi, t0r * wbi + t0i * wbr);
            s_Z[ZPAD(i2)] = make_float2(e0r + e1r, e0i + e1i);
            const float t1r = e0r - e1r, t1i = e0i - e1i;
            s_Z[ZPAD(i3)] = make_float2(t1r * wbr - t1i * wbi, t1r * wbi + t1i * wbr);
        }
        __syncthreads();
    }
    {
        const int i0 = tid << 1, i1 = i0 | 1;
        const float2 u = s_Z[ZPAD(i0)];
        const float2 v = s_Z[ZPAD(i1)];
        s_Z[ZPAD(i0)] = make_float2(u.x + v.x, u.y + v.y);
        s_Z[ZPAD(i1)] = make_float2(u.x - v.x, u.y - v.y);
    }
    __syncthreads();

    const float scale = 1.0f / (float)MM;
    float2* o2 = (float2*)out + (size_t)h * MM;
    #pragma unroll
    for (int q = 0; q < 2; ++q) {
        const int m = tid + q * 1024;
        const int r = (int)(__brev((unsigned)m) >> 21);
        const float2 z = s_Z[ZPAD(r)];
        o2[m] = make_float2(z.x * scale, z.y * scale);
    }
}

extern "C" void kernel_launch(void* const* d_in, const int* in_sizes, int n_in,
                              void* d_out, int out_size, void* d_ws, size_t ws_size,
                              hipStream_t stream) {
    const float* log_dt = (const float*)d_in[0];
    const float* w_re   = (const float*)d_in[1];
    const float* w_im   = (const float*)d_in[2];
    const float* B_re   = (const float*)d_in[3];
    const float* B_im   = (const float*)d_in[4];
    const float* P_re   = (const float*)d_in[5];
    const float* P_im   = (const float*)d_in[6];
    const float* C_re   = (const float*)d_in[7];
    const float* C_im   = (const float*)d_in[8];
    float* out = (float*)d_out;

    const size_t need = (size_t)HH * WS_STRIDE * sizeof(float2);   // ~8.4 MB
    if (ws_size >= need) {
        float2* Kws = (float2*)d_ws;
        cauchy_kernel<<<dim3(HH * 2), dim3(256), 0, stream>>>(
            log_dt, w_re, w_im, B_re, B_im, P_re, P_im, C_re, C_im, Kws);
        ifft_kernel<<<dim3(HH), dim3(256), 0, stream>>>(Kws, out);
    } else {
        ssknplr_fused<<<dim3(HH), dim3(1024), 0, stream>>>(
            log_dt, w_re, w_im, B_re, B_im, P_re, P_im, C_re, C_im, out);
    }
}

// Round 9
// 40.911 us; speedup vs baseline: 1.0268x; 1.0268x over previous
//
#include <hip/hip_runtime.h>
#include <hip/hip_bf16.h>
#include <math.h>

// S4 SSKernelNPLR, fully fused per-head (r7 structure), phase 2 with
// GUARANTEED packed fp32 via inline-asm v_pk_fma_f32 / v_pk_mul_f32.
//   phase 1: per-h pole params (13 scalars incl. negated copies, dt-folded),
//            duplicated halves, packed as 7 x float4 in LDS.
//   phase 2: Cauchy + Woodbury at 2049 rfft nodes; bins (tid, tid+1024) in
//            the two halves of v2f regs. mdim = fma(t,-2,wi) = -dim makes all
//            complex-MAC terms positive-fma with the stored negated copies.
//            z = 2i*tan(pi*l/L); tan via HW v_sin/v_cos (revolutions, <0.25).
//   phase 2.5: Hermitian recombination -> half-size complex spectrum.
//   phase 3: 2048-pt radix-2 DIF inverse FFT, two stages fused per barrier,
//            on-the-fly HW-trans twiddles (no table).
//   output: x[2m]=Re z[m]/M, x[2m+1]=Im z[m]/M, coalesced float2 stores.
// 1024 thr/block, 2 blocks/CU, __launch_bounds__(1024,8). LDS ~24.6 KB.
// Dims hardcoded: H=512, N=64, R=1, CH=1, L=4096.

#define HH   512
#define NN   64
#define LLEN 4096
#define MM   2048
#define NTHREADS 1024
#define ZPAD(i) ((i) + ((i) >> 4))

typedef float v2f __attribute__((ext_vector_type(2)));

__device__ __forceinline__ float sinr(float r) { return __builtin_amdgcn_sinf(r); }
__device__ __forceinline__ float cosr(float r) { return __builtin_amdgcn_cosf(r); }
__device__ __forceinline__ float rcpf(float x) { return __builtin_amdgcn_rcpf(x); }

__device__ __forceinline__ void pk_fma_acc(v2f& acc, v2f a, v2f b) {
    asm("v_pk_fma_f32 %0, %1, %2, %0" : "+v"(acc) : "v"(a), "v"(b));
}
__device__ __forceinline__ v2f pk_fma(v2f a, v2f b, v2f c) {
    v2f d; asm("v_pk_fma_f32 %0, %1, %2, %3" : "=v"(d) : "v"(a), "v"(b), "v"(c));
    return d;
}
__device__ __forceinline__ v2f pk_mul(v2f a, v2f b) {
    v2f d; asm("v_pk_mul_f32 %0, %1, %2" : "=v"(d) : "v"(a), "v"(b));
    return d;
}

__global__ __launch_bounds__(NTHREADS, 8) void ssknplr_kernel(
    const float* __restrict__ log_dt,
    const float* __restrict__ w_re, const float* __restrict__ w_im,
    const float* __restrict__ B_re, const float* __restrict__ B_im,
    const float* __restrict__ P_re, const float* __restrict__ P_im,
    const float* __restrict__ C_re, const float* __restrict__ C_im,
    float* __restrict__ out)
{
    // per-pole duplicated scalars packed as float4 pairs:
    // f0={wi,wi,-wr,-wr} f1={wr2,wr2,v00r,v00r} f2={v00i,v00i,-v00i,-v00i}
    // f3={v01r,v01r,v01i,v01i} f4={-v01i,-v01i,v10r,v10r}
    // f5={v10i,v10i,-v10i,-v10i} f6={v11,v11,0,0}   (all v* are dt-folded)
    __shared__ float4 s_p4[NN][7];          // 7 KB
    __shared__ float2 s_Z[ZPAD(MM) + 1];    // ~17.4 KB padded spectrum

    const int h   = blockIdx.x;
    const int tid = threadIdx.x;

    // ---- phase 1: per-head pole data ----
    if (tid < NN) {
        const int n   = tid;
        const int idx = h * NN + n;
        const float dt = expf(log_dt[h]);
        const float wr = w_re[idx] * dt;
        const float wi = w_im[idx] * dt;
        const float Br = B_re[idx], Bi = B_im[idx];
        const float Pr = P_re[idx], Pi = P_im[idx];
        const float Cr = C_re[idx], Ci = C_im[idx];
        const float v00r = dt * (Br * Cr - Bi * Ci);
        const float v00i = dt * (Br * Ci + Bi * Cr);
        const float v01r = dt * (Br * Pr + Bi * Pi);   // B*conj(P)
        const float v01i = dt * (Bi * Pr - Br * Pi);
        const float v10r = dt * (Pr * Cr - Pi * Ci);
        const float v10i = dt * (Pr * Ci + Pi * Cr);
        const float v11  = dt * (Pr * Pr + Pi * Pi);
        s_p4[n][0] = make_float4(wi, wi, -wr, -wr);
        s_p4[n][1] = make_float4(wr * wr, wr * wr, v00r, v00r);
        s_p4[n][2] = make_float4(v00i, v00i, -v00i, -v00i);
        s_p4[n][3] = make_float4(v01r, v01r, v01i, v01i);
        s_p4[n][4] = make_float4(-v01i, -v01i, v10r, v10r);
        s_p4[n][5] = make_float4(v10i, v10i, -v10i, -v10i);
        s_p4[n][6] = make_float4(v11, v11, 0.0f, 0.0f);
    }
    __syncthreads();

    // ---- phase 2: Cauchy + Woodbury, packed over bins (tid, tid+1024) ----
    v2f tv;
    {
        const float rx = (float)tid * (1.0f / 8192.0f);
        const float ry = (float)(tid + 1024) * (1.0f / 8192.0f);
        tv.x = sinr(rx) * rcpf(cosr(rx));
        tv.y = sinr(ry) * rcpf(cosr(ry));
    }
    const v2f neg2 = {-2.0f, -2.0f};

    v2f a00r = {0.f,0.f}, a00i = {0.f,0.f}, a01r = {0.f,0.f}, a01i = {0.f,0.f};
    v2f a10r = {0.f,0.f}, a10i = {0.f,0.f}, a11r = {0.f,0.f}, a11i = {0.f,0.f};

    #pragma unroll 2
    for (int n = 0; n < NN; ++n) {
        const float4 f0 = s_p4[n][0];
        const float4 f1 = s_p4[n][1];
        const float4 f2 = s_p4[n][2];
        const float4 f3 = s_p4[n][3];
        const float4 f4 = s_p4[n][4];
        const float4 f5 = s_p4[n][5];
        const float4 f6 = s_p4[n][6];
        const v2f wiv   = {f0.x, f0.y}, nr    = {f0.z, f0.w};
        const v2f wr2   = {f1.x, f1.y}, v00r  = {f1.z, f1.w};
        const v2f v00i  = {f2.x, f2.y}, nv00i = {f2.z, f2.w};
        const v2f v01r  = {f3.x, f3.y}, v01i  = {f3.z, f3.w};
        const v2f nv01i = {f4.x, f4.y}, v10r  = {f4.z, f4.w};
        const v2f v10i  = {f5.x, f5.y}, nv10i = {f5.z, f5.w};
        const v2f v11   = {f6.x, f6.y};

        const v2f mdim = pk_fma(tv, neg2, wiv);          // wi - 2t = -dim
        const v2f den  = pk_fma(mdim, mdim, wr2);
        const float ip = rcpf(den.x * den.y);            // one rcp, both halves
        const v2f ipv  = {ip, ip};
        const v2f dsw  = {den.y, den.x};
        const v2f inv  = pk_mul(dsw, ipv);
        const v2f ur   = pk_mul(nr, inv);                // -wr/den
        const v2f ui   = pk_mul(mdim, inv);              // -dim/den

        pk_fma_acc(a00r, v00r, ur);  pk_fma_acc(a00r, nv00i, ui);
        pk_fma_acc(a00i, v00r, ui);  pk_fma_acc(a00i, v00i,  ur);
        pk_fma_acc(a01r, v01r, ur);  pk_fma_acc(a01r, nv01i, ui);
        pk_fma_acc(a01i, v01r, ui);  pk_fma_acc(a01i, v01i,  ur);
        pk_fma_acc(a10r, v10r, ur);  pk_fma_acc(a10r, nv10i, ui);
        pk_fma_acc(a10i, v10r, ui);  pk_fma_acc(a10i, v10i,  ur);
        pk_fma_acc(a11r, v11, ur);   pk_fma_acc(a11i, v11,   ui);
    }

    {   // Woodbury + bilinear factor (once per thread), unpack on store.
        const v2f dr = a11r + 1.0f;
        const v2f di = a11i;
        const v2f dd = __builtin_elementwise_fma(dr, dr, di * di);
        v2f dinv; dinv.x = rcpf(dd.x); dinv.y = rcpf(dd.y);
        const v2f numr = a01r * a10r - a01i * a10i;
        const v2f numi = a01r * a10i + a01i * a10r;
        const v2f cr = (numr * dr + numi * di) * dinv;
        const v2f ci = (numi * dr - numr * di) * dinv;
        const v2f Wr = a00r - cr;
        const v2f Wi = a00i - ci;
        const v2f Kr = __builtin_elementwise_fma(-tv, Wi, Wr);   // K = W*(1+i*t)
        const v2f Ki = __builtin_elementwise_fma( tv, Wr, Wi);
        s_Z[ZPAD(tid)] = make_float2(Kr.x, (tid == 0) ? 0.0f : Ki.x);
        s_Z[ZPAD(tid + 1024)] = make_float2(Kr.y, Ki.y);
    }
    // Nyquist bin K[M]: analytic z->inf limit, real part only
    if (tid == 0) {
        float sr = 0.f;
        for (int n = 0; n < NN; ++n) sr += s_p4[n][1].z;   // v00r
        s_Z[ZPAD(MM)] = make_float2(0.5f * sr, 0.0f);
    }
    __syncthreads();

    // ---- phase 2.5: Hermitian recombination -> half-size spectrum (in place) ----
    {
        const int k = tid;                    // 0..1023
        if (k == 0) {
            const float a = s_Z[ZPAD(0)].x;
            const float b = s_Z[ZPAD(MM)].x;
            s_Z[ZPAD(0)] = make_float2(0.5f * (a + b), 0.5f * (a - b));
            const float2 km = s_Z[ZPAD(MM / 2)];
            s_Z[ZPAD(MM / 2)] = make_float2(km.x, -km.y);
        } else {
            const float2 Ka = s_Z[ZPAD(k)];
            const float2 Kb = s_Z[ZPAD(MM - k)];
            const float rk = (float)k * (1.0f / 4096.0f);   // revolutions, < 0.25
            const float sk = sinr(rk);
            const float ck = cosr(rk);
            const float Pr = 0.5f * (Ka.x + Kb.x), Pi = 0.5f * (Ka.y - Kb.y);
            const float Dr = 0.5f * (Ka.x - Kb.x), Di = 0.5f * (Ka.y + Kb.y);
            const float al = sk * Dr + ck * Di;
            const float be = ck * Dr - sk * Di;
            s_Z[ZPAD(k)]      = make_float2(Pr - al, Pi + be);
            s_Z[ZPAD(MM - k)] = make_float2(Pr + al, be - Pi);
        }
    }
    __syncthreads();

    // ---- phase 3: 2048-pt inverse FFT, radix-2 DIF, TWO stages per barrier ----
    for (int s = 10; s >= 1; s -= 2) {
        const int H = 1 << s;
        const int Q = H >> 1;
        const float scale = rcpf((float)(2 * H));           // exact pow2
        if (tid < 512) {
            const int b    = tid;
            const int j    = b & (Q - 1);
            const int base = ((b >> (s - 1)) << (s + 1)) + j;
            const int i0 = base, i1 = base + Q, i2 = base + H, i3 = base + H + Q;
            const float rev = (float)j * scale;             // < 0.25
            const float c  = cosr(rev);
            const float sn = sinr(rev);
            const float wbr = c * c - sn * sn;              // wB = wA^2
            const float wbi = 2.0f * c * sn;
            const float2 u0 = s_Z[ZPAD(i0)];
            const float2 u1 = s_Z[ZPAD(i1)];
            const float2 u2 = s_Z[ZPAD(i2)];
            const float2 u3 = s_Z[ZPAD(i3)];
            const float a0r = u0.x + u2.x, a0i = u0.y + u2.y;
            const float d0r = u0.x - u2.x, d0i = u0.y - u2.y;
            const float a1r = u1.x + u3.x, a1i = u1.y + u3.y;
            const float d1r = u1.x - u3.x, d1i = u1.y - u3.y;
            const float e0r = d0r * c  - d0i * sn, e0i = d0r * sn + d0i * c;
            const float e1r = -(d1r * sn) - d1i * c, e1i = d1r * c - d1i * sn;
            s_Z[ZPAD(i0)] = make_float2(a0r + a1r, a0i + a1i);
            const float t0r = a0r - a1r, t0i = a0i - a1i;
            s_Z[ZPAD(i1)] = make_float2(t0r * wbr - t0i * wbi, t0r * wbi + t0i * wbr);
            s_Z[ZPAD(i2)] = make_float2(e0r + e1r, e0i + e1i);
            const float t1r = e0r - e1r, t1i = e0i - e1i;
            s_Z[ZPAD(i3)] = make_float2(t1r * wbr - t1i * wbi, t1r * wbi + t1i * wbr);
        }
        __syncthreads();
    }
    {   // final stage s=0: twiddle = 1, pure add/sub, all 1024 threads
        const int i0 = tid << 1, i1 = i0 | 1;
        const float2 u = s_Z[ZPAD(i0)];
        const float2 v = s_Z[ZPAD(i1)];
        s_Z[ZPAD(i0)] = make_float2(u.x + v.x, u.y + v.y);
        s_Z[ZPAD(i1)] = make_float2(u.x - v.x, u.y - v.y);
    }
    __syncthreads();

    // ---- output: z[m] = Zfinal[bitrev(m)]; x[2m]=Re/M, x[2m+1]=Im/M ----
    const float scale = 1.0f / (float)MM;
    float2* o2 = (float2*)out + (size_t)h * MM;
    #pragma unroll
    for (int q = 0; q < 2; ++q) {
        const int m = tid + q * NTHREADS;
        const int r = (int)(__brev((unsigned)m) >> 21);
        const float2 z = s_Z[ZPAD(r)];
        o2[m] = make_float2(z.x * scale, z.y * scale);
    }
}

extern "C" void kernel_launch(void* const* d_in, const int* in_sizes, int n_in,
                              void* d_out, int out_size, void* d_ws, size_t ws_size,
                              hipStream_t stream) {
    const float* log_dt = (const float*)d_in[0];
    const float* w_re   = (const float*)d_in[1];
    const float* w_im   = (const float*)d_in[2];
    const float* B_re   = (const float*)d_in[3];
    const float* B_im   = (const float*)d_in[4];
    const float* P_re   = (const float*)d_in[5];
    const float* P_im   = (const float*)d_in[6];
    const float* C_re   = (const float*)d_in[7];
    const float* C_im   = (const float*)d_in[8];
    float* out = (float*)d_out;

    ssknplr_kernel<<<dim3(HH), dim3(NTHREADS), 0, stream>>>(
        log_dt, w_re, w_im, B_re, B_im, P_re, P_im, C_re, C_im, out);
}

// Round 10
// 36.622 us; speedup vs baseline: 1.1471x; 1.1171x over previous
//
#include <hip/hip_runtime.h>
#include <hip/hip_bf16.h>
#include <math.h>

// S4 SSKernelNPLR, fully fused per-head. 512 threads/block, 4 bins/thread
// (two packed v2f chains) -> FFT pair-stages use ALL threads (r7 idled half),
// pole-table LDS broadcast stream per CU halves, ILP doubles.
//   phase 1: per-h pole params (dt-folded), duplicated halves, 5 x float4 LDS.
//   phase 2: Cauchy + Woodbury at 2049 rfft nodes, packed fp32 (compiler
//            v_pk_fma_f32 via __builtin_elementwise_fma; r9 showed inline-asm
//            pk REGRESSES vs compiler codegen). z = 2i*tan(pi*l/L); tan via
//            HW v_sin/v_cos (revolutions, <0.25); one rcp per pole per chain.
//   phase 2.5: Hermitian recombination -> half-size complex spectrum.
//   phase 3: 2048-pt radix-2 DIF inverse FFT, two stages fused per barrier
//            (512 butterfly-quads = all threads), HW-trans on-the-fly twiddles.
//   output: x[2m]=Re z[m]/M, x[2m+1]=Im z[m]/M, coalesced float2 stores.
// LDS ~22.4 KB; grid 512 x 512 thr = 2 blocks/CU (16 waves/CU, ILP-heavy).
// Dims hardcoded: H=512, N=64, R=1, CH=1, L=4096.

#define HH   512
#define NN   64
#define LLEN 4096
#define MM   2048
#define NTHREADS 512
#define ZPAD(i) ((i) + ((i) >> 4))

typedef float v2f __attribute__((ext_vector_type(2)));

__device__ __forceinline__ float sinr(float r) { return __builtin_amdgcn_sinf(r); }  // sin(2*pi*r)
__device__ __forceinline__ float cosr(float r) { return __builtin_amdgcn_cosf(r); }
__device__ __forceinline__ float rcpf(float x) { return __builtin_amdgcn_rcpf(x); }

__device__ __forceinline__ void cauchy_step(
    const v2f tv, const v2f mwi, const v2f nr, const v2f wr2,
    const v2f v00r, const v2f v00i, const v2f v01r, const v2f v01i,
    const v2f v10r, const v2f v10i, const v2f v11,
    v2f& a00r, v2f& a00i, v2f& a01r, v2f& a01i,
    v2f& a10r, v2f& a10i, v2f& a11r, v2f& a11i)
{
    const v2f dim = __builtin_elementwise_fma(tv, (v2f){2.0f, 2.0f}, mwi); // 2t - wi
    const v2f den = __builtin_elementwise_fma(dim, dim, wr2);
    const float ip = rcpf(den.x * den.y);      // one rcp for both halves
    v2f inv; inv.x = den.y * ip; inv.y = den.x * ip;
    const v2f ur = nr * inv;
    const v2f ui = -(dim * inv);
    a00r = __builtin_elementwise_fma( v00r, ur, a00r);
    a00r = __builtin_elementwise_fma(-v00i, ui, a00r);
    a00i = __builtin_elementwise_fma( v00r, ui, a00i);
    a00i = __builtin_elementwise_fma( v00i, ur, a00i);
    a01r = __builtin_elementwise_fma( v01r, ur, a01r);
    a01r = __builtin_elementwise_fma(-v01i, ui, a01r);
    a01i = __builtin_elementwise_fma( v01r, ui, a01i);
    a01i = __builtin_elementwise_fma( v01i, ur, a01i);
    a10r = __builtin_elementwise_fma( v10r, ur, a10r);
    a10r = __builtin_elementwise_fma(-v10i, ui, a10r);
    a10i = __builtin_elementwise_fma( v10r, ui, a10i);
    a10i = __builtin_elementwise_fma( v10i, ur, a10i);
    a11r = __builtin_elementwise_fma( v11,  ur, a11r);
    a11i = __builtin_elementwise_fma( v11,  ui, a11i);
}

__device__ __forceinline__ void woodbury_K(
    const v2f tv,
    const v2f a00r, const v2f a00i, const v2f a01r, const v2f a01i,
    const v2f a10r, const v2f a10i, const v2f a11r, const v2f a11i,
    v2f& Kr, v2f& Ki)
{
    const v2f dr = a11r + 1.0f;
    const v2f di = a11i;
    const v2f dd = __builtin_elementwise_fma(dr, dr, di * di);
    v2f dinv; dinv.x = rcpf(dd.x); dinv.y = rcpf(dd.y);
    const v2f numr = a01r * a10r - a01i * a10i;
    const v2f numi = a01r * a10i + a01i * a10r;
    const v2f cr = (numr * dr + numi * di) * dinv;
    const v2f ci = (numi * dr - numr * di) * dinv;
    const v2f Wr = a00r - cr;
    const v2f Wi = a00i - ci;
    Kr = __builtin_elementwise_fma(-tv, Wi, Wr);   // K = W * (1 + i*t)
    Ki = __builtin_elementwise_fma( tv, Wr, Wi);
}

__global__ __launch_bounds__(NTHREADS, 4) void ssknplr_kernel(
    const float* __restrict__ log_dt,
    const float* __restrict__ w_re, const float* __restrict__ w_im,
    const float* __restrict__ B_re, const float* __restrict__ B_im,
    const float* __restrict__ P_re, const float* __restrict__ P_im,
    const float* __restrict__ C_re, const float* __restrict__ C_im,
    float* __restrict__ out)
{
    // duplicated per-pole scalars, 5 x float4 (all v* dt-folded):
    // f0={-wi,-wi,-wr,-wr} f1={wr2,wr2,v00r,v00r} f2={v00i,v00i,v01r,v01r}
    // f3={v01i,v01i,v10r,v10r} f4={v10i,v10i,v11,v11}
    __shared__ float4 s_p4[NN][5];          // 5 KB
    __shared__ float2 s_Z[ZPAD(MM) + 1];    // ~17.4 KB padded spectrum

    const int h   = blockIdx.x;
    const int tid = threadIdx.x;

    // ---- phase 1: per-head pole data ----
    if (tid < NN) {
        const int n   = tid;
        const int idx = h * NN + n;
        const float dt = expf(log_dt[h]);
        const float wr = w_re[idx] * dt;
        const float wi = w_im[idx] * dt;
        const float Br = B_re[idx], Bi = B_im[idx];
        const float Pr = P_re[idx], Pi = P_im[idx];
        const float Cr = C_re[idx], Ci = C_im[idx];
        const float v00r = dt * (Br * Cr - Bi * Ci);
        const float v00i = dt * (Br * Ci + Bi * Cr);
        const float v01r = dt * (Br * Pr + Bi * Pi);   // B*conj(P)
        const float v01i = dt * (Bi * Pr - Br * Pi);
        const float v10r = dt * (Pr * Cr - Pi * Ci);
        const float v10i = dt * (Pr * Ci + Pi * Cr);
        const float v11  = dt * (Pr * Pr + Pi * Pi);
        s_p4[n][0] = make_float4(-wi, -wi, -wr, -wr);
        s_p4[n][1] = make_float4(wr * wr, wr * wr, v00r, v00r);
        s_p4[n][2] = make_float4(v00i, v00i, v01r, v01r);
        s_p4[n][3] = make_float4(v01i, v01i, v10r, v10r);
        s_p4[n][4] = make_float4(v10i, v10i, v11, v11);
    }
    __syncthreads();

    // ---- phase 2: Cauchy + Woodbury, 4 bins/thread in two packed chains ----
    // chain A: bins (tid, tid+1024); chain B: bins (tid+512, tid+1536)
    v2f tvA, tvB;
    {
        const float rA0 = (float)tid           * (1.0f / 8192.0f);
        const float rA1 = (float)(tid + 1024)  * (1.0f / 8192.0f);
        const float rB0 = (float)(tid + 512)   * (1.0f / 8192.0f);
        const float rB1 = (float)(tid + 1536)  * (1.0f / 8192.0f);
        tvA.x = sinr(rA0) * rcpf(cosr(rA0));
        tvA.y = sinr(rA1) * rcpf(cosr(rA1));
        tvB.x = sinr(rB0) * rcpf(cosr(rB0));
        tvB.y = sinr(rB1) * rcpf(cosr(rB1));
    }

    v2f A00r = {0.f,0.f}, A00i = {0.f,0.f}, A01r = {0.f,0.f}, A01i = {0.f,0.f};
    v2f A10r = {0.f,0.f}, A10i = {0.f,0.f}, A11r = {0.f,0.f}, A11i = {0.f,0.f};
    v2f B00r = {0.f,0.f}, B00i = {0.f,0.f}, B01r = {0.f,0.f}, B01i = {0.f,0.f};
    v2f B10r = {0.f,0.f}, B10i = {0.f,0.f}, B11r = {0.f,0.f}, B11i = {0.f,0.f};

    for (int n = 0; n < NN; ++n) {
        const float4 f0 = s_p4[n][0];
        const float4 f1 = s_p4[n][1];
        const float4 f2 = s_p4[n][2];
        const float4 f3 = s_p4[n][3];
        const float4 f4 = s_p4[n][4];
        const v2f mwi  = {f0.x, f0.y}, nr   = {f0.z, f0.w};
        const v2f wr2  = {f1.x, f1.y}, v00r = {f1.z, f1.w};
        const v2f v00i = {f2.x, f2.y}, v01r = {f2.z, f2.w};
        const v2f v01i = {f3.x, f3.y}, v10r = {f3.z, f3.w};
        const v2f v10i = {f4.x, f4.y}, v11  = {f4.z, f4.w};
        cauchy_step(tvA, mwi, nr, wr2, v00r, v00i, v01r, v01i, v10r, v10i, v11,
                    A00r, A00i, A01r, A01i, A10r, A10i, A11r, A11i);
        cauchy_step(tvB, mwi, nr, wr2, v00r, v00i, v01r, v01i, v10r, v10i, v11,
                    B00r, B00i, B01r, B01i, B10r, B10i, B11r, B11i);
    }

    {
        v2f Kr, Ki;
        woodbury_K(tvA, A00r, A00i, A01r, A01i, A10r, A10i, A11r, A11i, Kr, Ki);
        s_Z[ZPAD(tid)]        = make_float2(Kr.x, (tid == 0) ? 0.0f : Ki.x);
        s_Z[ZPAD(tid + 1024)] = make_float2(Kr.y, Ki.y);
    }
    {
        v2f Kr, Ki;
        woodbury_K(tvB, B00r, B00i, B01r, B01i, B10r, B10i, B11r, B11i, Kr, Ki);
        s_Z[ZPAD(tid + 512)]  = make_float2(Kr.x, Ki.x);
        s_Z[ZPAD(tid + 1536)] = make_float2(Kr.y, Ki.y);
    }
    // Nyquist bin K[M]: analytic z->inf limit, real part only
    if (tid == 0) {
        float sr = 0.f;
        for (int n = 0; n < NN; ++n) sr += s_p4[n][1].z;   // v00r
        s_Z[ZPAD(MM)] = make_float2(0.5f * sr, 0.0f);
    }
    __syncthreads();

    // ---- phase 2.5: Hermitian recombination -> half-size spectrum (in place) ----
    #pragma unroll
    for (int q = 0; q < 2; ++q) {
        const int k = tid + (q << 9);         // 0..1023
        if (k == 0) {
            const float a = s_Z[ZPAD(0)].x;
            const float b = s_Z[ZPAD(MM)].x;
            s_Z[ZPAD(0)] = make_float2(0.5f * (a + b), 0.5f * (a - b));
            const float2 km = s_Z[ZPAD(MM / 2)];
            s_Z[ZPAD(MM / 2)] = make_float2(km.x, -km.y);
        } else {
            const float2 Ka = s_Z[ZPAD(k)];
            const float2 Kb = s_Z[ZPAD(MM - k)];
            const float rk = (float)k * (1.0f / 4096.0f);   // revolutions, < 0.25
            const float sk = sinr(rk);
            const float ck = cosr(rk);
            const float Pr = 0.5f * (Ka.x + Kb.x), Pi = 0.5f * (Ka.y - Kb.y);
            const float Dr = 0.5f * (Ka.x - Kb.x), Di = 0.5f * (Ka.y + Kb.y);
            const float al = sk * Dr + ck * Di;
            const float be = ck * Dr - sk * Di;
            s_Z[ZPAD(k)]      = make_float2(Pr - al, Pi + be);
            s_Z[ZPAD(MM - k)] = make_float2(Pr + al, be - Pi);
        }
    }
    __syncthreads();

    // ---- phase 3: 2048-pt inverse FFT, radix-2 DIF, TWO stages per barrier ----
    // 512 butterfly-quads per round -> ALL threads active.
    for (int s = 10; s >= 1; s -= 2) {
        const int H = 1 << s;
        const int Q = H >> 1;
        const float scale = rcpf((float)(2 * H));           // exact pow2
        {
            const int b    = tid;
            const int j    = b & (Q - 1);
            const int base = ((b >> (s - 1)) << (s + 1)) + j;
            const int i0 = base, i1 = base + Q, i2 = base + H, i3 = base + H + Q;
            const float rev = (float)j * scale;             // < 0.25
            const float c  = cosr(rev);
            const float sn = sinr(rev);
            const float wbr = c * c - sn * sn;              // wB = wA^2
            const float wbi = 2.0f * c * sn;
            const float2 u0 = s_Z[ZPAD(i0)];
            const float2 u1 = s_Z[ZPAD(i1)];
            const float2 u2 = s_Z[ZPAD(i2)];
            const float2 u3 = s_Z[ZPAD(i3)];
            // level A (stage s): (i0,i2) with wA ; (i1,i3) with i*wA
            const float a0r = u0.x + u2.x, a0i = u0.y + u2.y;
            const float d0r = u0.x - u2.x, d0i = u0.y - u2.y;
            const float a1r = u1.x + u3.x, a1i = u1.y + u3.y;
            const float d1r = u1.x - u3.x, d1i = u1.y - u3.y;
            const float e0r = d0r * c  - d0i * sn, e0i = d0r * sn + d0i * c;
            const float e1r = -(d1r * sn) - d1i * c, e1i = d1r * c - d1i * sn;
            // level B (stage s-1): (i0,i1) and (i2,i3), both with wB
            s_Z[ZPAD(i0)] = make_float2(a0r + a1r, a0i + a1i);
            const float t0r = a0r - a1r, t0i = a0i - a1i;
            s_Z[ZPAD(i1)] = make_float2(t0r * wbr - t0i * wbi, t0r * wbi + t0i * wbr);
            s_Z[ZPAD(i2)] = make_float2(e0r + e1r, e0i + e1i);
            const float t1r = e0r - e1r, t1i = e0i - e1i;
            s_Z[ZPAD(i3)] = make_float2(t1r * wbr - t1i * wbi, t1r * wbi + t1i * wbr);
        }
        __syncthreads();
    }
    {   // final stage s=0: twiddle = 1, pure add/sub, 2 butterflies/thread
        #pragma unroll
        for (int q = 0; q < 2; ++q) {
            const int b  = tid + (q << 9);
            const int i0 = b << 1, i1 = i0 | 1;
            const float2 u = s_Z[ZPAD(i0)];
            const float2 v = s_Z[ZPAD(i1)];
            s_Z[ZPAD(i0)] = make_float2(u.x + v.x, u.y + v.y);
            s_Z[ZPAD(i1)] = make_float2(u.x - v.x, u.y - v.y);
        }
    }
    __syncthreads();

    // ---- output: z[m] = Zfinal[bitrev11(m)]; x[2m]=Re/M, x[2m+1]=Im/M ----
    const float scale = 1.0f / (float)MM;
    float2* o2 = (float2*)out + (size_t)h * MM;
    #pragma unroll
    for (int q = 0; q < 4; ++q) {
        const int m = tid + (q << 9);
        const int r = (int)(__brev((unsigned)m) >> 21);
        const float2 z = s_Z[ZPAD(r)];
        o2[m] = make_float2(z.x * scale, z.y * scale);
    }
}

extern "C" void kernel_launch(void* const* d_in, const int* in_sizes, int n_in,
                              void* d_out, int out_size, void* d_ws, size_t ws_size,
                              hipStream_t stream) {
    const float* log_dt = (const float*)d_in[0];
    const float* w_re   = (const float*)d_in[1];
    const float* w_im   = (const float*)d_in[2];
    const float* B_re   = (const float*)d_in[3];
    const float* B_im   = (const float*)d_in[4];
    const float* P_re   = (const float*)d_in[5];
    const float* P_im   = (const float*)d_in[6];
    const float* C_re   = (const float*)d_in[7];
    const float* C_im   = (const float*)d_in[8];
    float* out = (float*)d_out;

    ssknplr_kernel<<<dim3(HH), dim3(NTHREADS), 0, stream>>>(
        log_dt, w_re, w_im, B_re, B_im, P_re, P_im, C_re, C_im, out);
}

// Round 11
// 36.397 us; speedup vs baseline: 1.1541x; 1.0062x over previous
//
#include <hip/hip_runtime.h>
#include <hip/hip_bf16.h>
#include <math.h>

// S4 SSKernelNPLR, fully fused per-head. 512 threads/block, 4 bins/thread in
// MIRROR PAIRS: chain A = bins (tid, 2048-tid), chain B = (512+tid, 1536-tid),
// using tan(pi*(M-l)/L) = 1/tan(pi*l/L) (cot from the same HW sin/cos).
// Hermitian recombination then happens IN REGISTERS at the end of phase 2 --
// the old phase-2.5 barrier + LDS round-trip is deleted.
//   phase 1: per-h pole params (dt-folded), duplicated halves, 5 x float4 LDS.
//   phase 2: Cauchy + Woodbury at 2049 rfft nodes, packed fp32 (compiler
//            v_pk_fma_f32; r9 showed inline-asm pk regresses). One rcp per
//            pole per chain. -> in-register recombination -> Z in LDS.
//   phase 3: 2048-pt radix-2 DIF inverse FFT, two stages fused per barrier
//            (512 butterfly-quads = all threads), HW-trans on-the-fly twiddles.
//   output: x[2m]=Re z[m]/M, x[2m+1]=Im z[m]/M, coalesced float2 stores.
// LDS ~22.4 KB; grid 512 x 512 thr; 8 barriers total.
// Dims hardcoded: H=512, N=64, R=1, CH=1, L=4096.

#define HH   512
#define NN   64
#define LLEN 4096
#define MM   2048
#define NTHREADS 512
#define ZPAD(i) ((i) + ((i) >> 4))

typedef float v2f __attribute__((ext_vector_type(2)));

__device__ __forceinline__ float sinr(float r) { return __builtin_amdgcn_sinf(r); }  // sin(2*pi*r)
__device__ __forceinline__ float cosr(float r) { return __builtin_amdgcn_cosf(r); }
__device__ __forceinline__ float rcpf(float x) { return __builtin_amdgcn_rcpf(x); }

__device__ __forceinline__ void cauchy_step(
    const v2f tv, const v2f mwi, const v2f nr, const v2f wr2,
    const v2f v00r, const v2f v00i, const v2f v01r, const v2f v01i,
    const v2f v10r, const v2f v10i, const v2f v11,
    v2f& a00r, v2f& a00i, v2f& a01r, v2f& a01i,
    v2f& a10r, v2f& a10i, v2f& a11r, v2f& a11i)
{
    const v2f dim = __builtin_elementwise_fma(tv, (v2f){2.0f, 2.0f}, mwi); // 2t - wi
    const v2f den = __builtin_elementwise_fma(dim, dim, wr2);
    const float ip = rcpf(den.x * den.y);      // one rcp for both halves
    v2f inv; inv.x = den.y * ip; inv.y = den.x * ip;
    const v2f ur = nr * inv;
    const v2f ui = -(dim * inv);
    a00r = __builtin_elementwise_fma( v00r, ur, a00r);
    a00r = __builtin_elementwise_fma(-v00i, ui, a00r);
    a00i = __builtin_elementwise_fma( v00r, ui, a00i);
    a00i = __builtin_elementwise_fma( v00i, ur, a00i);
    a01r = __builtin_elementwise_fma( v01r, ur, a01r);
    a01r = __builtin_elementwise_fma(-v01i, ui, a01r);
    a01i = __builtin_elementwise_fma( v01r, ui, a01i);
    a01i = __builtin_elementwise_fma( v01i, ur, a01i);
    a10r = __builtin_elementwise_fma( v10r, ur, a10r);
    a10r = __builtin_elementwise_fma(-v10i, ui, a10r);
    a10i = __builtin_elementwise_fma( v10r, ui, a10i);
    a10i = __builtin_elementwise_fma( v10i, ur, a10i);
    a11r = __builtin_elementwise_fma( v11,  ur, a11r);
    a11i = __builtin_elementwise_fma( v11,  ui, a11i);
}

__device__ __forceinline__ void woodbury_K(
    const v2f tv,
    const v2f a00r, const v2f a00i, const v2f a01r, const v2f a01i,
    const v2f a10r, const v2f a10i, const v2f a11r, const v2f a11i,
    v2f& Kr, v2f& Ki)
{
    const v2f dr = a11r + 1.0f;
    const v2f di = a11i;
    const v2f dd = __builtin_elementwise_fma(dr, dr, di * di);
    v2f dinv; dinv.x = rcpf(dd.x); dinv.y = rcpf(dd.y);
    const v2f numr = a01r * a10r - a01i * a10i;
    const v2f numi = a01r * a10i + a01i * a10r;
    const v2f cr = (numr * dr + numi * di) * dinv;
    const v2f ci = (numi * dr - numr * di) * dinv;
    const v2f Wr = a00r - cr;
    const v2f Wi = a00i - ci;
    Kr = __builtin_elementwise_fma(-tv, Wi, Wr);   // K = W * (1 + i*t)
    Ki = __builtin_elementwise_fma( tv, Wr, Wi);
}

__global__ __launch_bounds__(NTHREADS, 4) void ssknplr_kernel(
    const float* __restrict__ log_dt,
    const float* __restrict__ w_re, const float* __restrict__ w_im,
    const float* __restrict__ B_re, const float* __restrict__ B_im,
    const float* __restrict__ P_re, const float* __restrict__ P_im,
    const float* __restrict__ C_re, const float* __restrict__ C_im,
    float* __restrict__ out)
{
    // duplicated per-pole scalars, 5 x float4 (all v* dt-folded):
    // f0={-wi,-wi,-wr,-wr} f1={wr2,wr2,v00r,v00r} f2={v00i,v00i,v01r,v01r}
    // f3={v01i,v01i,v10r,v10r} f4={v10i,v10i,v11,v11}
    __shared__ float4 s_p4[NN][5];          // 5 KB
    __shared__ float2 s_Z[ZPAD(MM) + 1];    // ~17.4 KB padded spectrum

    const int h   = blockIdx.x;
    const int tid = threadIdx.x;

    // ---- phase 1: per-head pole data ----
    if (tid < NN) {
        const int n   = tid;
        const int idx = h * NN + n;
        const float dt = expf(log_dt[h]);
        const float wr = w_re[idx] * dt;
        const float wi = w_im[idx] * dt;
        const float Br = B_re[idx], Bi = B_im[idx];
        const float Pr = P_re[idx], Pi = P_im[idx];
        const float Cr = C_re[idx], Ci = C_im[idx];
        const float v00r = dt * (Br * Cr - Bi * Ci);
        const float v00i = dt * (Br * Ci + Bi * Cr);
        const float v01r = dt * (Br * Pr + Bi * Pi);   // B*conj(P)
        const float v01i = dt * (Bi * Pr - Br * Pi);
        const float v10r = dt * (Pr * Cr - Pi * Ci);
        const float v10i = dt * (Pr * Ci + Pi * Cr);
        const float v11  = dt * (Pr * Pr + Pi * Pi);
        s_p4[n][0] = make_float4(-wi, -wi, -wr, -wr);
        s_p4[n][1] = make_float4(wr * wr, wr * wr, v00r, v00r);
        s_p4[n][2] = make_float4(v00i, v00i, v01r, v01r);
        s_p4[n][3] = make_float4(v01i, v01i, v10r, v10r);
        s_p4[n][4] = make_float4(v10i, v10i, v11, v11);
    }
    __syncthreads();

    // ---- phase 2: Cauchy + Woodbury, mirror-pair chains ----
    // chain A: bins (tid, 2048-tid)   [tid==0: (0, 1024)]
    // chain B: bins (512+tid, 1536-tid)
    v2f tvA, tvB;
    {
        const float rA = (float)tid         * (1.0f / 8192.0f);
        const float rB = (float)(tid + 512) * (1.0f / 8192.0f);
        const float sA = sinr(rA), cA = cosr(rA);
        const float sB = sinr(rB), cB = cosr(rB);
        tvA.x = sA * rcpf(cA);                              // tan
        tvA.y = (tid == 0) ? 1.0f : cA * rcpf(sA);          // cot (bin 2048-tid); tid0 -> bin 1024, tan(pi/4)=1
        tvB.x = sB * rcpf(cB);
        tvB.y = cB * rcpf(sB);
    }

    v2f A00r = {0.f,0.f}, A00i = {0.f,0.f}, A01r = {0.f,0.f}, A01i = {0.f,0.f};
    v2f A10r = {0.f,0.f}, A10i = {0.f,0.f}, A11r = {0.f,0.f}, A11i = {0.f,0.f};
    v2f B00r = {0.f,0.f}, B00i = {0.f,0.f}, B01r = {0.f,0.f}, B01i = {0.f,0.f};
    v2f B10r = {0.f,0.f}, B10i = {0.f,0.f}, B11r = {0.f,0.f}, B11i = {0.f,0.f};

    for (int n = 0; n < NN; ++n) {
        const float4 f0 = s_p4[n][0];
        const float4 f1 = s_p4[n][1];
        const float4 f2 = s_p4[n][2];
        const float4 f3 = s_p4[n][3];
        const float4 f4 = s_p4[n][4];
        const v2f mwi  = {f0.x, f0.y}, nr   = {f0.z, f0.w};
        const v2f wr2  = {f1.x, f1.y}, v00r = {f1.z, f1.w};
        const v2f v00i = {f2.x, f2.y}, v01r = {f2.z, f2.w};
        const v2f v01i = {f3.x, f3.y}, v10r = {f3.z, f3.w};
        const v2f v10i = {f4.x, f4.y}, v11  = {f4.z, f4.w};
        cauchy_step(tvA, mwi, nr, wr2, v00r, v00i, v01r, v01i, v10r, v10i, v11,
                    A00r, A00i, A01r, A01i, A10r, A10i, A11r, A11i);
        cauchy_step(tvB, mwi, nr, wr2, v00r, v00i, v01r, v01i, v10r, v10i, v11,
                    B00r, B00i, B01r, B01i, B10r, B10i, B11r, B11i);
    }

    // ---- in-register Hermitian recombination -> Z (no phase-2.5 pass) ----
    // pair (k, Mk): Ka=K[k]=(Kr.x,Ki.x), Kb=K[Mk]=(Kr.y,Ki.y), (c,s)=e^{2pi i k/L}
    {
        v2f Kr, Ki;
        woodbury_K(tvA, A00r, A00i, A01r, A01i, A10r, A10i, A11r, A11i, Kr, Ki);
        if (tid == 0) {
            // chain A holds K[0] (.x) and K[1024] (.y); Nyquist analytic.
            float sr = 0.f;
            for (int n = 0; n < NN; ++n) sr += s_p4[n][1].z;   // v00r
            const float KN = 0.5f * sr;
            s_Z[ZPAD(0)]    = make_float2(0.5f * (Kr.x + KN), 0.5f * (Kr.x - KN));
            s_Z[ZPAD(1024)] = make_float2(Kr.y, -Ki.y);        // Z[M/2] = conj(K[M/2])
        } else {
            const int k = tid, Mk = MM - tid;
            const float rk = (float)k * (1.0f / 4096.0f);
            const float sk = sinr(rk), ck = cosr(rk);
            const float Pr = 0.5f * (Kr.x + Kr.y), Pi = 0.5f * (Ki.x - Ki.y);
            const float Dr = 0.5f * (Kr.x - Kr.y), Di = 0.5f * (Ki.x + Ki.y);
            const float al = sk * Dr + ck * Di;
            const float be = ck * Dr - sk * Di;
            s_Z[ZPAD(k)]  = make_float2(Pr - al, Pi + be);
            s_Z[ZPAD(Mk)] = make_float2(Pr + al, be - Pi);
        }
    }
    {
        v2f Kr, Ki;
        woodbury_K(tvB, B00r, B00i, B01r, B01i, B10r, B10i, B11r, B11i, Kr, Ki);
        const int k = 512 + tid, Mk = 1536 - tid;
        const float rk = (float)k * (1.0f / 4096.0f);
        const float sk = sinr(rk), ck = cosr(rk);
        const float Pr = 0.5f * (Kr.x + Kr.y), Pi = 0.5f * (Ki.x - Ki.y);
        const float Dr = 0.5f * (Kr.x - Kr.y), Di = 0.5f * (Ki.x + Ki.y);
        const float al = sk * Dr + ck * Di;
        const float be = ck * Dr - sk * Di;
        s_Z[ZPAD(k)]  = make_float2(Pr - al, Pi + be);
        s_Z[ZPAD(Mk)] = make_float2(Pr + al, be - Pi);
    }
    __syncthreads();

    // ---- phase 3: 2048-pt inverse FFT, radix-2 DIF, TWO stages per barrier ----
    // 512 butterfly-quads per round -> ALL threads active.
    for (int s = 10; s >= 1; s -= 2) {
        const int H = 1 << s;
        const int Q = H >> 1;
        const float scale = rcpf((float)(2 * H));           // exact pow2
        {
            const int b    = tid;
            const int j    = b & (Q - 1);
            const int base = ((b >> (s - 1)) << (s + 1)) + j;
            const int i0 = base, i1 = base + Q, i2 = base + H, i3 = base + H + Q;
            const float rev = (float)j * scale;             // < 0.25
            const float c  = cosr(rev);
            const float sn = sinr(rev);
            const float wbr = c * c - sn * sn;              // wB = wA^2
            const float wbi = 2.0f * c * sn;
            const float2 u0 = s_Z[ZPAD(i0)];
            const float2 u1 = s_Z[ZPAD(i1)];
            const float2 u2 = s_Z[ZPAD(i2)];
            const float2 u3 = s_Z[ZPAD(i3)];
            // level A (stage s): (i0,i2) with wA ; (i1,i3) with i*wA
            const float a0r = u0.x + u2.x, a0i = u0.y + u2.y;
            const float d0r = u0.x - u2.x, d0i = u0.y - u2.y;
            const float a1r = u1.x + u3.x, a1i = u1.y + u3.y;
            const float d1r = u1.x - u3.x, d1i = u1.y - u3.y;
            const float e0r = d0r * c  - d0i * sn, e0i = d0r * sn + d0i * c;
            const float e1r = -(d1r * sn) - d1i * c, e1i = d1r * c - d1i * sn;
            // level B (stage s-1): (i0,i1) and (i2,i3), both with wB
            s_Z[ZPAD(i0)] = make_float2(a0r + a1r, a0i + a1i);
            const float t0r = a0r - a1r, t0i = a0i - a1i;
            s_Z[ZPAD(i1)] = make_float2(t0r * wbr - t0i * wbi, t0r * wbi + t0i * wbr);
            s_Z[ZPAD(i2)] = make_float2(e0r + e1r, e0i + e1i);
            const float t1r = e0r - e1r, t1i = e0i - e1i;
            s_Z[ZPAD(i3)] = make_float2(t1r * wbr - t1i * wbi, t1r * wbi + t1i * wbr);
        }
        __syncthreads();
    }
    {   // final stage s=0: twiddle = 1, pure add/sub, 2 butterflies/thread
        #pragma unroll
        for (int q = 0; q < 2; ++q) {
            const int b  = tid + (q << 9);
            const int i0 = b << 1, i1 = i0 | 1;
            const float2 u = s_Z[ZPAD(i0)];
            const float2 v = s_Z[ZPAD(i1)];
            s_Z[ZPAD(i0)] = make_float2(u.x + v.x, u.y + v.y);
            s_Z[ZPAD(i1)] = make_float2(u.x - v.x, u.y - v.y);
        }
    }
    __syncthreads();

    // ---- output: z[m] = Zfinal[bitrev11(m)]; x[2m]=Re/M, x[2m+1]=Im/M ----
    const float scale = 1.0f / (float)MM;
    float2* o2 = (float2*)out + (size_t)h * MM;
    #pragma unroll
    for (int q = 0; q < 4; ++q) {
        const int m = tid + (q << 9);
        const int r = (int)(__brev((unsigned)m) >> 21);
        const float2 z = s_Z[ZPAD(r)];
        o2[m] = make_float2(z.x * scale, z.y * scale);
    }
}

extern "C" void kernel_launch(void* const* d_in, const int* in_sizes, int n_in,
                              void* d_out, int out_size, void* d_ws, size_t ws_size,
                              hipStream_t stream) {
    const float* log_dt = (const float*)d_in[0];
    const float* w_re   = (const float*)d_in[1];
    const float* w_im   = (const float*)d_in[2];
    const float* B_re   = (const float*)d_in[3];
    const float* B_im   = (const float*)d_in[4];
    const float* P_re   = (const float*)d_in[5];
    const float* P_im   = (const float*)d_in[6];
    const float* C_re   = (const float*)d_in[7];
    const float* C_im   = (const float*)d_in[8];
    float* out = (float*)d_out;

    ssknplr_kernel<<<dim3(HH), dim3(NTHREADS), 0, stream>>>(
        log_dt, w_re, w_im, B_re, B_im, P_re, P_im, C_re, C_im, out);
}

// Round 12
// 36.016 us; speedup vs baseline: 1.1663x; 1.0106x over previous
//
#include <hip/hip_runtime.h>
#include <hip/hip_bf16.h>
#include <math.h>

// S4 SSKernelNPLR, fully fused per-head. 512 threads/block, 4 bins/thread in
// MIRROR PAIRS: chain A = bins (tid, 2048-tid), chain B = (512+tid, 1536-tid),
// using tan(pi*(M-l)/L) = 1/tan(pi*l/L). Hermitian recombination happens IN
// REGISTERS at the end of phase 2 (no phase-2.5 pass).
//   phase 1: per-h pole params (dt-folded), duplicated halves, 5 x float4 LDS.
//   phase 2: Cauchy + Woodbury at 2049 rfft nodes, packed fp32 (compiler
//            v_pk_fma_f32; r9 showed inline-asm pk regresses). One rcp per
//            pole per chain. -> in-register recombination -> Z in LDS.
//   phase 3: 2048-pt radix-2 DIF inverse FFT, two stages fused per barrier
//            (512 butterfly-quads = all threads), HW-trans on-the-fly
//            twiddles. FINAL s=0 STAGE FUSED INTO THE OUTPUT GATHER:
//            r(q) for m=tid+q*512 differs only in bits 0-1 of bitrev11(m), so
//            each thread reads 4 consecutive s_Z entries and emits
//            (z0+z1, z2+z3, z0-z1, z2-z3) -- one whole round + barrier saved.
//   output: x[2m]=Re z[m]/M, x[2m+1]=Im z[m]/M, coalesced float2 stores.
// LDS ~22.4 KB; grid 512 x 512 thr; 7 barriers total.
// Dims hardcoded: H=512, N=64, R=1, CH=1, L=4096.

#define HH   512
#define NN   64
#define LLEN 4096
#define MM   2048
#define NTHREADS 512
#define ZPAD(i) ((i) + ((i) >> 4))

typedef float v2f __attribute__((ext_vector_type(2)));

__device__ __forceinline__ float sinr(float r) { return __builtin_amdgcn_sinf(r); }  // sin(2*pi*r)
__device__ __forceinline__ float cosr(float r) { return __builtin_amdgcn_cosf(r); }
__device__ __forceinline__ float rcpf(float x) { return __builtin_amdgcn_rcpf(x); }

__device__ __forceinline__ void cauchy_step(
    const v2f tv, const v2f mwi, const v2f nr, const v2f wr2,
    const v2f v00r, const v2f v00i, const v2f v01r, const v2f v01i,
    const v2f v10r, const v2f v10i, const v2f v11,
    v2f& a00r, v2f& a00i, v2f& a01r, v2f& a01i,
    v2f& a10r, v2f& a10i, v2f& a11r, v2f& a11i)
{
    const v2f dim = __builtin_elementwise_fma(tv, (v2f){2.0f, 2.0f}, mwi); // 2t - wi
    const v2f den = __builtin_elementwise_fma(dim, dim, wr2);
    const float ip = rcpf(den.x * den.y);      // one rcp for both halves
    v2f inv; inv.x = den.y * ip; inv.y = den.x * ip;
    const v2f ur = nr * inv;
    const v2f ui = -(dim * inv);
    a00r = __builtin_elementwise_fma( v00r, ur, a00r);
    a00r = __builtin_elementwise_fma(-v00i, ui, a00r);
    a00i = __builtin_elementwise_fma( v00r, ui, a00i);
    a00i = __builtin_elementwise_fma( v00i, ur, a00i);
    a01r = __builtin_elementwise_fma( v01r, ur, a01r);
    a01r = __builtin_elementwise_fma(-v01i, ui, a01r);
    a01i = __builtin_elementwise_fma( v01r, ui, a01i);
    a01i = __builtin_elementwise_fma( v01i, ur, a01i);
    a10r = __builtin_elementwise_fma( v10r, ur, a10r);
    a10r = __builtin_elementwise_fma(-v10i, ui, a10r);
    a10i = __builtin_elementwise_fma( v10r, ui, a10i);
    a10i = __builtin_elementwise_fma( v10i, ur, a10i);
    a11r = __builtin_elementwise_fma( v11,  ur, a11r);
    a11i = __builtin_elementwise_fma( v11,  ui, a11i);
}

__device__ __forceinline__ void woodbury_K(
    const v2f tv,
    const v2f a00r, const v2f a00i, const v2f a01r, const v2f a01i,
    const v2f a10r, const v2f a10i, const v2f a11r, const v2f a11i,
    v2f& Kr, v2f& Ki)
{
    const v2f dr = a11r + 1.0f;
    const v2f di = a11i;
    const v2f dd = __builtin_elementwise_fma(dr, dr, di * di);
    v2f dinv; dinv.x = rcpf(dd.x); dinv.y = rcpf(dd.y);
    const v2f numr = a01r * a10r - a01i * a10i;
    const v2f numi = a01r * a10i + a01i * a10r;
    const v2f cr = (numr * dr + numi * di) * dinv;
    const v2f ci = (numi * dr - numr * di) * dinv;
    const v2f Wr = a00r - cr;
    const v2f Wi = a00i - ci;
    Kr = __builtin_elementwise_fma(-tv, Wi, Wr);   // K = W * (1 + i*t)
    Ki = __builtin_elementwise_fma( tv, Wr, Wi);
}

__global__ __launch_bounds__(NTHREADS, 4) void ssknplr_kernel(
    const float* __restrict__ log_dt,
    const float* __restrict__ w_re, const float* __restrict__ w_im,
    const float* __restrict__ B_re, const float* __restrict__ B_im,
    const float* __restrict__ P_re, const float* __restrict__ P_im,
    const float* __restrict__ C_re, const float* __restrict__ C_im,
    float* __restrict__ out)
{
    // duplicated per-pole scalars, 5 x float4 (all v* dt-folded):
    // f0={-wi,-wi,-wr,-wr} f1={wr2,wr2,v00r,v00r} f2={v00i,v00i,v01r,v01r}
    // f3={v01i,v01i,v10r,v10r} f4={v10i,v10i,v11,v11}
    __shared__ float4 s_p4[NN][5];          // 5 KB
    __shared__ float2 s_Z[ZPAD(MM) + 1];    // ~17.4 KB padded spectrum

    const int h   = blockIdx.x;
    const int tid = threadIdx.x;

    // ---- phase 1: per-head pole data ----
    if (tid < NN) {
        const int n   = tid;
        const int idx = h * NN + n;
        const float dt = expf(log_dt[h]);
        const float wr = w_re[idx] * dt;
        const float wi = w_im[idx] * dt;
        const float Br = B_re[idx], Bi = B_im[idx];
        const float Pr = P_re[idx], Pi = P_im[idx];
        const float Cr = C_re[idx], Ci = C_im[idx];
        const float v00r = dt * (Br * Cr - Bi * Ci);
        const float v00i = dt * (Br * Ci + Bi * Cr);
        const float v01r = dt * (Br * Pr + Bi * Pi);   // B*conj(P)
        const float v01i = dt * (Bi * Pr - Br * Pi);
        const float v10r = dt * (Pr * Cr - Pi * Ci);
        const float v10i = dt * (Pr * Ci + Pi * Cr);
        const float v11  = dt * (Pr * Pr + Pi * Pi);
        s_p4[n][0] = make_float4(-wi, -wi, -wr, -wr);
        s_p4[n][1] = make_float4(wr * wr, wr * wr, v00r, v00r);
        s_p4[n][2] = make_float4(v00i, v00i, v01r, v01r);
        s_p4[n][3] = make_float4(v01i, v01i, v10r, v10r);
        s_p4[n][4] = make_float4(v10i, v10i, v11, v11);
    }
    __syncthreads();

    // ---- phase 2: Cauchy + Woodbury, mirror-pair chains ----
    // chain A: bins (tid, 2048-tid)   [tid==0: (0, 1024)]
    // chain B: bins (512+tid, 1536-tid)
    v2f tvA, tvB;
    {
        const float rA = (float)tid         * (1.0f / 8192.0f);
        const float rB = (float)(tid + 512) * (1.0f / 8192.0f);
        const float sA = sinr(rA), cA = cosr(rA);
        const float sB = sinr(rB), cB = cosr(rB);
        tvA.x = sA * rcpf(cA);                              // tan
        tvA.y = (tid == 0) ? 1.0f : cA * rcpf(sA);          // cot (bin 2048-tid); tid0 -> bin 1024
        tvB.x = sB * rcpf(cB);
        tvB.y = cB * rcpf(sB);
    }

    v2f A00r = {0.f,0.f}, A00i = {0.f,0.f}, A01r = {0.f,0.f}, A01i = {0.f,0.f};
    v2f A10r = {0.f,0.f}, A10i = {0.f,0.f}, A11r = {0.f,0.f}, A11i = {0.f,0.f};
    v2f B00r = {0.f,0.f}, B00i = {0.f,0.f}, B01r = {0.f,0.f}, B01i = {0.f,0.f};
    v2f B10r = {0.f,0.f}, B10i = {0.f,0.f}, B11r = {0.f,0.f}, B11i = {0.f,0.f};

    #pragma unroll 4
    for (int n = 0; n < NN; ++n) {
        const float4 f0 = s_p4[n][0];
        const float4 f1 = s_p4[n][1];
        const float4 f2 = s_p4[n][2];
        const float4 f3 = s_p4[n][3];
        const float4 f4 = s_p4[n][4];
        const v2f mwi  = {f0.x, f0.y}, nr   = {f0.z, f0.w};
        const v2f wr2  = {f1.x, f1.y}, v00r = {f1.z, f1.w};
        const v2f v00i = {f2.x, f2.y}, v01r = {f2.z, f2.w};
        const v2f v01i = {f3.x, f3.y}, v10r = {f3.z, f3.w};
        const v2f v10i = {f4.x, f4.y}, v11  = {f4.z, f4.w};
        cauchy_step(tvA, mwi, nr, wr2, v00r, v00i, v01r, v01i, v10r, v10i, v11,
                    A00r, A00i, A01r, A01i, A10r, A10i, A11r, A11i);
        cauchy_step(tvB, mwi, nr, wr2, v00r, v00i, v01r, v01i, v10r, v10i, v11,
                    B00r, B00i, B01r, B01i, B10r, B10i, B11r, B11i);
    }

    // ---- in-register Hermitian recombination -> Z (no phase-2.5 pass) ----
    {
        v2f Kr, Ki;
        woodbury_K(tvA, A00r, A00i, A01r, A01i, A10r, A10i, A11r, A11i, Kr, Ki);
        if (tid == 0) {
            float sr = 0.f;
            for (int n = 0; n < NN; ++n) sr += s_p4[n][1].z;   // v00r
            const float KN = 0.5f * sr;                        // analytic Nyquist
            s_Z[ZPAD(0)]    = make_float2(0.5f * (Kr.x + KN), 0.5f * (Kr.x - KN));
            s_Z[ZPAD(1024)] = make_float2(Kr.y, -Ki.y);        // Z[M/2] = conj(K[M/2])
        } else {
            const int k = tid, Mk = MM - tid;
            const float rk = (float)k * (1.0f / 4096.0f);
            const float sk = sinr(rk), ck = cosr(rk);
            const float Pr = 0.5f * (Kr.x + Kr.y), Pi = 0.5f * (Ki.x - Ki.y);
            const float Dr = 0.5f * (Kr.x - Kr.y), Di = 0.5f * (Ki.x + Ki.y);
            const float al = sk * Dr + ck * Di;
            const float be = ck * Dr - sk * Di;
            s_Z[ZPAD(k)]  = make_float2(Pr - al, Pi + be);
            s_Z[ZPAD(Mk)] = make_float2(Pr + al, be - Pi);
        }
    }
    {
        v2f Kr, Ki;
        woodbury_K(tvB, B00r, B00i, B01r, B01i, B10r, B10i, B11r, B11i, Kr, Ki);
        const int k = 512 + tid, Mk = 1536 - tid;
        const float rk = (float)k * (1.0f / 4096.0f);
        const float sk = sinr(rk), ck = cosr(rk);
        const float Pr = 0.5f * (Kr.x + Kr.y), Pi = 0.5f * (Ki.x - Ki.y);
        const float Dr = 0.5f * (Kr.x - Kr.y), Di = 0.5f * (Ki.x + Ki.y);
        const float al = sk * Dr + ck * Di;
        const float be = ck * Dr - sk * Di;
        s_Z[ZPAD(k)]  = make_float2(Pr - al, Pi + be);
        s_Z[ZPAD(Mk)] = make_float2(Pr + al, be - Pi);
    }
    __syncthreads();

    // ---- phase 3: 2048-pt inverse FFT, radix-2 DIF, TWO stages per barrier ----
    // Rounds (10,9)(8,7)(6,5)(4,3)(2,1); stage 0 is fused into the output.
    for (int s = 10; s >= 1; s -= 2) {
        const int H = 1 << s;
        const int Q = H >> 1;
        const float scale = rcpf((float)(2 * H));           // exact pow2
        {
            const int b    = tid;
            const int j    = b & (Q - 1);
            const int base = ((b >> (s - 1)) << (s + 1)) + j;
            const int i0 = base, i1 = base + Q, i2 = base + H, i3 = base + H + Q;
            const float rev = (float)j * scale;             // < 0.25
            const float c  = cosr(rev);
            const float sn = sinr(rev);
            const float wbr = c * c - sn * sn;              // wB = wA^2
            const float wbi = 2.0f * c * sn;
            const float2 u0 = s_Z[ZPAD(i0)];
            const float2 u1 = s_Z[ZPAD(i1)];
            const float2 u2 = s_Z[ZPAD(i2)];
            const float2 u3 = s_Z[ZPAD(i3)];
            // level A (stage s): (i0,i2) with wA ; (i1,i3) with i*wA
            const float a0r = u0.x + u2.x, a0i = u0.y + u2.y;
            const float d0r = u0.x - u2.x, d0i = u0.y - u2.y;
            const float a1r = u1.x + u3.x, a1i = u1.y + u3.y;
            const float d1r = u1.x - u3.x, d1i = u1.y - u3.y;
            const float e0r = d0r * c  - d0i * sn, e0i = d0r * sn + d0i * c;
            const float e1r = -(d1r * sn) - d1i * c, e1i = d1r * c - d1i * sn;
            // level B (stage s-1): (i0,i1) and (i2,i3), both with wB
            s_Z[ZPAD(i0)] = make_float2(a0r + a1r, a0i + a1i);
            const float t0r = a0r - a1r, t0i = a0i - a1i;
            s_Z[ZPAD(i1)] = make_float2(t0r * wbr - t0i * wbi, t0r * wbi + t0i * wbr);
            s_Z[ZPAD(i2)] = make_float2(e0r + e1r, e0i + e1i);
            const float t1r = e0r - e1r, t1i = e0i - e1i;
            s_Z[ZPAD(i3)] = make_float2(t1r * wbr - t1i * wbi, t1r * wbi + t1i * wbr);
        }
        __syncthreads();
    }

    // ---- output with FUSED final stage ----
    // m = tid + q*512 -> r = bitrev11(m) = r0 | {q0:0, q1:2, q2:1, q3:3},
    // r0 = bitrev11(tid) (bits 0-1 clear). Final stage value at r:
    //   X[r] = Zprev[r&~1] + (r even ? + : -) Zprev[r|1].
    // So: out[tid]=z0+z1, out[tid+512]=z2+z3, out[tid+1024]=z0-z1,
    //     out[tid+1536]=z2-z3 (all * 1/M), z0..z3 consecutive in s_Z.
    {
        const float scale = 1.0f / (float)MM;
        const int r0 = (int)(__brev((unsigned)tid) >> 21);  // bits 0-1 clear
        const int zb = ZPAD(r0);                            // r0..r0+3 ZP-consecutive
        const float2 z0 = s_Z[zb + 0];
        const float2 z1 = s_Z[zb + 1];
        const float2 z2 = s_Z[zb + 2];
        const float2 z3 = s_Z[zb + 3];
        float2* o2 = (float2*)out + (size_t)h * MM;
        o2[tid]        = make_float2((z0.x + z1.x) * scale, (z0.y + z1.y) * scale);
        o2[tid + 512]  = make_float2((z2.x + z3.x) * scale, (z2.y + z3.y) * scale);
        o2[tid + 1024] = make_float2((z0.x - z1.x) * scale, (z0.y - z1.y) * scale);
        o2[tid + 1536] = make_float2((z2.x - z3.x) * scale, (z2.y - z3.y) * scale);
    }
}

extern "C" void kernel_launch(void* const* d_in, const int* in_sizes, int n_in,
                              void* d_out, int out_size, void* d_ws, size_t ws_size,
                              hipStream_t stream) {
    const float* log_dt = (const float*)d_in[0];
    const float* w_re   = (const float*)d_in[1];
    const float* w_im   = (const float*)d_in[2];
    const float* B_re   = (const float*)d_in[3];
    const float* B_im   = (const float*)d_in[4];
    const float* P_re   = (const float*)d_in[5];
    const float* P_im   = (const float*)d_in[6];
    const float* C_re   = (const float*)d_in[7];
    const float* C_im   = (const float*)d_in[8];
    float* out = (float*)d_out;

    ssknplr_kernel<<<dim3(HH), dim3(NTHREADS), 0, stream>>>(
        log_dt, w_re, w_im, B_re, B_im, P_re, P_im, C_re, C_im, out);
}

// Round 13
// 35.048 us; speedup vs baseline: 1.1986x; 1.0276x over previous
//
#include <hip/hip_runtime.h>
#include <hip/hip_bf16.h>
#include <math.h>

// S4 SSKernelNPLR, fully fused per-head. 512 threads/block, 4 bins/thread in
// MIRROR PAIRS: chain A = bins (tid, 2048-tid), chain B = (512+tid, 1536-tid).
// Hermitian recombination in registers at the end of phase 2.
//   phase 1: per-h pole params (dt-folded), UN-DUPLICATED: 10 floats/pole as
//            2 x float4 + 1 x float2 -> 3 LDS reads/pole (was 5 duplicated;
//            v2f splats {x,x} fold into VOP3P op_sel, costing no movs).
//   phase 2: Cauchy + Woodbury at 2049 rfft nodes, packed fp32 (compiler
//            v_pk_fma_f32). One rcp per pole per chain. tan/cot via HW
//            v_sin/v_cos (revolutions, < 0.25).
//   phase 3: 2048-pt radix-2 DIF inverse FFT, two stages fused per barrier
//            (512 butterfly-quads = all threads), on-the-fly HW twiddles.
//            Final s=0 stage fused into the output gather (r12).
//   output: x[2m]=Re z[m]/M, x[2m+1]=Im z[m]/M, coalesced float2 stores.
// LDS ~20 KB; grid 512 x 512 thr; 7 barriers total.
// Dims hardcoded: H=512, N=64, R=1, CH=1, L=4096.

#define HH   512
#define NN   64
#define LLEN 4096
#define MM   2048
#define NTHREADS 512
#define ZPAD(i) ((i) + ((i) >> 4))

typedef float v2f __attribute__((ext_vector_type(2)));

__device__ __forceinline__ float sinr(float r) { return __builtin_amdgcn_sinf(r); }  // sin(2*pi*r)
__device__ __forceinline__ float cosr(float r) { return __builtin_amdgcn_cosf(r); }
__device__ __forceinline__ float rcpf(float x) { return __builtin_amdgcn_rcpf(x); }

__device__ __forceinline__ void cauchy_step(
    const v2f tv, const v2f mwi, const v2f nr, const v2f wr2,
    const v2f v00r, const v2f v00i, const v2f v01r, const v2f v01i,
    const v2f v10r, const v2f v10i, const v2f v11,
    v2f& a00r, v2f& a00i, v2f& a01r, v2f& a01i,
    v2f& a10r, v2f& a10i, v2f& a11r, v2f& a11i)
{
    const v2f dim = __builtin_elementwise_fma(tv, (v2f){2.0f, 2.0f}, mwi); // 2t - wi
    const v2f den = __builtin_elementwise_fma(dim, dim, wr2);
    const float ip = rcpf(den.x * den.y);      // one rcp for both halves
    v2f inv; inv.x = den.y * ip; inv.y = den.x * ip;
    const v2f ur = nr * inv;
    const v2f ui = -(dim * inv);
    a00r = __builtin_elementwise_fma( v00r, ur, a00r);
    a00r = __builtin_elementwise_fma(-v00i, ui, a00r);
    a00i = __builtin_elementwise_fma( v00r, ui, a00i);
    a00i = __builtin_elementwise_fma( v00i, ur, a00i);
    a01r = __builtin_elementwise_fma( v01r, ur, a01r);
    a01r = __builtin_elementwise_fma(-v01i, ui, a01r);
    a01i = __builtin_elementwise_fma( v01r, ui, a01i);
    a01i = __builtin_elementwise_fma( v01i, ur, a01i);
    a10r = __builtin_elementwise_fma( v10r, ur, a10r);
    a10r = __builtin_elementwise_fma(-v10i, ui, a10r);
    a10i = __builtin_elementwise_fma( v10r, ui, a10i);
    a10i = __builtin_elementwise_fma( v10i, ur, a10i);
    a11r = __builtin_elementwise_fma( v11,  ur, a11r);
    a11i = __builtin_elementwise_fma( v11,  ui, a11i);
}

__device__ __forceinline__ void woodbury_K(
    const v2f tv,
    const v2f a00r, const v2f a00i, const v2f a01r, const v2f a01i,
    const v2f a10r, const v2f a10i, const v2f a11r, const v2f a11i,
    v2f& Kr, v2f& Ki)
{
    const v2f dr = a11r + 1.0f;
    const v2f di = a11i;
    const v2f dd = __builtin_elementwise_fma(dr, dr, di * di);
    v2f dinv; dinv.x = rcpf(dd.x); dinv.y = rcpf(dd.y);
    const v2f numr = a01r * a10r - a01i * a10i;
    const v2f numi = a01r * a10i + a01i * a10r;
    const v2f cr = (numr * dr + numi * di) * dinv;
    const v2f ci = (numi * dr - numr * di) * dinv;
    const v2f Wr = a00r - cr;
    const v2f Wi = a00i - ci;
    Kr = __builtin_elementwise_fma(-tv, Wi, Wr);   // K = W * (1 + i*t)
    Ki = __builtin_elementwise_fma( tv, Wr, Wi);
}

__global__ __launch_bounds__(NTHREADS, 4) void ssknplr_kernel(
    const float* __restrict__ log_dt,
    const float* __restrict__ w_re, const float* __restrict__ w_im,
    const float* __restrict__ B_re, const float* __restrict__ B_im,
    const float* __restrict__ P_re, const float* __restrict__ P_im,
    const float* __restrict__ C_re, const float* __restrict__ C_im,
    float* __restrict__ out)
{
    // UN-duplicated per-pole scalars (all v* dt-folded):
    // q0 = {-wi, -wr, wr2, v00r}; q1 = {v00i, v01r, v01i, v10r}; q2 = {v10i, v11}
    __shared__ float4 s_q0[NN];             // 1 KB
    __shared__ float4 s_q1[NN];             // 1 KB
    __shared__ float2 s_q2[NN];             // 0.5 KB
    __shared__ float2 s_Z[ZPAD(MM) + 1];    // ~17.4 KB padded spectrum

    const int h   = blockIdx.x;
    const int tid = threadIdx.x;

    // ---- phase 1: per-head pole data ----
    if (tid < NN) {
        const int n   = tid;
        const int idx = h * NN + n;
        const float dt = expf(log_dt[h]);
        const float wr = w_re[idx] * dt;
        const float wi = w_im[idx] * dt;
        const float Br = B_re[idx], Bi = B_im[idx];
        const float Pr = P_re[idx], Pi = P_im[idx];
        const float Cr = C_re[idx], Ci = C_im[idx];
        const float v00r = dt * (Br * Cr - Bi * Ci);
        const float v00i = dt * (Br * Ci + Bi * Cr);
        const float v01r = dt * (Br * Pr + Bi * Pi);   // B*conj(P)
        const float v01i = dt * (Bi * Pr - Br * Pi);
        const float v10r = dt * (Pr * Cr - Pi * Ci);
        const float v10i = dt * (Pr * Ci + Pi * Cr);
        const float v11  = dt * (Pr * Pr + Pi * Pi);
        s_q0[n] = make_float4(-wi, -wr, wr * wr, v00r);
        s_q1[n] = make_float4(v00i, v01r, v01i, v10r);
        s_q2[n] = make_float2(v10i, v11);
    }
    __syncthreads();

    // ---- phase 2: Cauchy + Woodbury, mirror-pair chains ----
    // chain A: bins (tid, 2048-tid)   [tid==0: (0, 1024)]
    // chain B: bins (512+tid, 1536-tid)
    v2f tvA, tvB;
    {
        const float rA = (float)tid         * (1.0f / 8192.0f);
        const float rB = (float)(tid + 512) * (1.0f / 8192.0f);
        const float sA = sinr(rA), cA = cosr(rA);
        const float sB = sinr(rB), cB = cosr(rB);
        tvA.x = sA * rcpf(cA);                              // tan
        tvA.y = (tid == 0) ? 1.0f : cA * rcpf(sA);          // cot (bin 2048-tid); tid0 -> bin 1024
        tvB.x = sB * rcpf(cB);
        tvB.y = cB * rcpf(sB);
    }

    v2f A00r = {0.f,0.f}, A00i = {0.f,0.f}, A01r = {0.f,0.f}, A01i = {0.f,0.f};
    v2f A10r = {0.f,0.f}, A10i = {0.f,0.f}, A11r = {0.f,0.f}, A11i = {0.f,0.f};
    v2f B00r = {0.f,0.f}, B00i = {0.f,0.f}, B01r = {0.f,0.f}, B01i = {0.f,0.f};
    v2f B10r = {0.f,0.f}, B10i = {0.f,0.f}, B11r = {0.f,0.f}, B11i = {0.f,0.f};

    #pragma unroll 4
    for (int n = 0; n < NN; ++n) {
        const float4 q0 = s_q0[n];
        const float4 q1 = s_q1[n];
        const float2 q2 = s_q2[n];
        // v2f splats: folded into VOP3P op_sel (no movs expected)
        const v2f mwi  = {q0.x, q0.x}, nr   = {q0.y, q0.y}, wr2 = {q0.z, q0.z};
        const v2f v00r = {q0.w, q0.w}, v00i = {q1.x, q1.x};
        const v2f v01r = {q1.y, q1.y}, v01i = {q1.z, q1.z};
        const v2f v10r = {q1.w, q1.w}, v10i = {q2.x, q2.x};
        const v2f v11  = {q2.y, q2.y};
        cauchy_step(tvA, mwi, nr, wr2, v00r, v00i, v01r, v01i, v10r, v10i, v11,
                    A00r, A00i, A01r, A01i, A10r, A10i, A11r, A11i);
        cauchy_step(tvB, mwi, nr, wr2, v00r, v00i, v01r, v01i, v10r, v10i, v11,
                    B00r, B00i, B01r, B01i, B10r, B10i, B11r, B11i);
    }

    // ---- in-register Hermitian recombination -> Z (no phase-2.5 pass) ----
    {
        v2f Kr, Ki;
        woodbury_K(tvA, A00r, A00i, A01r, A01i, A10r, A10i, A11r, A11i, Kr, Ki);
        if (tid == 0) {
            float sr = 0.f;
            for (int n = 0; n < NN; ++n) sr += s_q0[n].w;      // v00r
            const float KN = 0.5f * sr;                        // analytic Nyquist
            s_Z[ZPAD(0)]    = make_float2(0.5f * (Kr.x + KN), 0.5f * (Kr.x - KN));
            s_Z[ZPAD(1024)] = make_float2(Kr.y, -Ki.y);        // Z[M/2] = conj(K[M/2])
        } else {
            const int k = tid, Mk = MM - tid;
            const float rk = (float)k * (1.0f / 4096.0f);
            const float sk = sinr(rk), ck = cosr(rk);
            const float Pr = 0.5f * (Kr.x + Kr.y), Pi = 0.5f * (Ki.x - Ki.y);
            const float Dr = 0.5f * (Kr.x - Kr.y), Di = 0.5f * (Ki.x + Ki.y);
            const float al = sk * Dr + ck * Di;
            const float be = ck * Dr - sk * Di;
            s_Z[ZPAD(k)]  = make_float2(Pr - al, Pi + be);
            s_Z[ZPAD(Mk)] = make_float2(Pr + al, be - Pi);
        }
    }
    {
        v2f Kr, Ki;
        woodbury_K(tvB, B00r, B00i, B01r, B01i, B10r, B10i, B11r, B11i, Kr, Ki);
        const int k = 512 + tid, Mk = 1536 - tid;
        const float rk = (float)k * (1.0f / 4096.0f);
        const float sk = sinr(rk), ck = cosr(rk);
        const float Pr = 0.5f * (Kr.x + Kr.y), Pi = 0.5f * (Ki.x - Ki.y);
        const float Dr = 0.5f * (Kr.x - Kr.y), Di = 0.5f * (Ki.x + Ki.y);
        const float al = sk * Dr + ck * Di;
        const float be = ck * Dr - sk * Di;
        s_Z[ZPAD(k)]  = make_float2(Pr - al, Pi + be);
        s_Z[ZPAD(Mk)] = make_float2(Pr + al, be - Pi);
    }
    __syncthreads();

    // ---- phase 3: 2048-pt inverse FFT, radix-2 DIF, TWO stages per barrier ----
    // Rounds (10,9)(8,7)(6,5)(4,3)(2,1); stage 0 is fused into the output.
    for (int s = 10; s >= 1; s -= 2) {
        const int H = 1 << s;
        const int Q = H >> 1;
        const float scale = rcpf((float)(2 * H));           // exact pow2
        {
            const int b    = tid;
            const int j    = b & (Q - 1);
            const int base = ((b >> (s - 1)) << (s + 1)) + j;
            const int i0 = base, i1 = base + Q, i2 = base + H, i3 = base + H + Q;
            const float rev = (float)j * scale;             // < 0.25
            const float c  = cosr(rev);
            const float sn = sinr(rev);
            const float wbr = c * c - sn * sn;              // wB = wA^2
            const float wbi = 2.0f * c * sn;
            const float2 u0 = s_Z[ZPAD(i0)];
            const float2 u1 = s_Z[ZPAD(i1)];
            const float2 u2 = s_Z[ZPAD(i2)];
            const float2 u3 = s_Z[ZPAD(i3)];
            // level A (stage s): (i0,i2) with wA ; (i1,i3) with i*wA
            const float a0r = u0.x + u2.x, a0i = u0.y + u2.y;
            const float d0r = u0.x - u2.x, d0i = u0.y - u2.y;
            const float a1r = u1.x + u3.x, a1i = u1.y + u3.y;
            const float d1r = u1.x - u3.x, d1i = u1.y - u3.y;
            const float e0r = d0r * c  - d0i * sn, e0i = d0r * sn + d0i * c;
            const float e1r = -(d1r * sn) - d1i * c, e1i = d1r * c - d1i * sn;
            // level B (stage s-1): (i0,i1) and (i2,i3), both with wB
            s_Z[ZPAD(i0)] = make_float2(a0r + a1r, a0i + a1i);
            const float t0r = a0r - a1r, t0i = a0i - a1i;
            s_Z[ZPAD(i1)] = make_float2(t0r * wbr - t0i * wbi, t0r * wbi + t0i * wbr);
            s_Z[ZPAD(i2)] = make_float2(e0r + e1r, e0i + e1i);
            const float t1r = e0r - e1r, t1i = e0i - e1i;
            s_Z[ZPAD(i3)] = make_float2(t1r * wbr - t1i * wbi, t1r * wbi + t1i * wbr);
        }
        __syncthreads();
    }

    // ---- output with FUSED final stage (r12) ----
    // m = tid + q*512 -> r = bitrev11(m) = r0 | {q0:0, q1:2, q2:1, q3:3},
    // r0 = bitrev11(tid) (bits 0-1 clear):
    //   out[tid]=z0+z1, out[tid+512]=z2+z3, out[tid+1024]=z0-z1,
    //   out[tid+1536]=z2-z3 (all * 1/M), z0..z3 consecutive in s_Z.
    {
        const float scale = 1.0f / (float)MM;
        const int r0 = (int)(__brev((unsigned)tid) >> 21);  // bits 0-1 clear
        const int zb = ZPAD(r0);                            // r0..r0+3 ZP-consecutive
        const float2 z0 = s_Z[zb + 0];
        const float2 z1 = s_Z[zb + 1];
        const float2 z2 = s_Z[zb + 2];
        const float2 z3 = s_Z[zb + 3];
        float2* o2 = (float2*)out + (size_t)h * MM;
        o2[tid]        = make_float2((z0.x + z1.x) * scale, (z0.y + z1.y) * scale);
        o2[tid + 512]  = make_float2((z2.x + z3.x) * scale, (z2.y + z3.y) * scale);
        o2[tid + 1024] = make_float2((z0.x - z1.x) * scale, (z0.y - z1.y) * scale);
        o2[tid + 1536] = make_float2((z2.x - z3.x) * scale, (z2.y - z3.y) * scale);
    }
}

extern "C" void kernel_launch(void* const* d_in, const int* in_sizes, int n_in,
                              void* d_out, int out_size, void* d_ws, size_t ws_size,
                              hipStream_t stream) {
    const float* log_dt = (const float*)d_in[0];
    const float* w_re   = (const float*)d_in[1];
    const float* w_im   = (const float*)d_in[2];
    const float* B_re   = (const float*)d_in[3];
    const float* B_im   = (const float*)d_in[4];
    const float* P_re   = (const float*)d_in[5];
    const float* P_im   = (const float*)d_in[6];
    const float* C_re   = (const float*)d_in[7];
    const float* C_im   = (const float*)d_in[8];
    float* out = (float*)d_out;

    ssknplr_kernel<<<dim3(HH), dim3(NTHREADS), 0, stream>>>(
        log_dt, w_re, w_im, B_re, B_im, P_re, P_im, C_re, C_im, out);
}